// Round 5
// baseline (2739.823 us; speedup 1.0000x reference)
//
#include <hip/hip_runtime.h>
#include <hip/hip_bf16.h>

#define B_ 16
#define L_ 96
#define N_ 1024
#define EMB_ 64

typedef __hip_bfloat16 bf16;
typedef __attribute__((ext_vector_type(4))) float f32x4;
typedef __attribute__((ext_vector_type(8))) short s16x8;

// ================= fp32 GEMM (NN), small setup mats only =================
__global__ __launch_bounds__(256) void gemm_nn(
    const float* __restrict__ A, const float* __restrict__ Bm, float* __restrict__ C,
    int M, int N, int K, int lda, int ldb, int ldc, const float* __restrict__ bias)
{
    __shared__ float As[64][17];
    __shared__ __align__(16) float Bs[16][64];
    const int tid = threadIdx.x;
    const int tx = tid & 15, ty = tid >> 4;
    const int row0 = blockIdx.y * 64, col0 = blockIdx.x * 64;
    float acc[4][4] = {};
    const int ak = tid & 15, ar = tid >> 4;
    const int bc = tid & 63, bk = tid >> 6;
    for (int k0 = 0; k0 < K; k0 += 16) {
#pragma unroll
        for (int i = 0; i < 4; ++i) {
            int r = ar + i * 16;
            int gr = row0 + r, gk = k0 + ak;
            As[r][ak] = (gr < M && gk < K) ? A[(size_t)gr * lda + gk] : 0.f;
        }
#pragma unroll
        for (int i = 0; i < 4; ++i) {
            int kk = bk + i * 4;
            int gk = k0 + kk, gc = col0 + bc;
            Bs[kk][bc] = (gk < K && gc < N) ? Bm[(size_t)gk * ldb + gc] : 0.f;
        }
        __syncthreads();
#pragma unroll
        for (int kk = 0; kk < 16; ++kk) {
            float4 b4 = *reinterpret_cast<const float4*>(&Bs[kk][tx * 4]);
            float a0 = As[ty * 4 + 0][kk];
            float a1 = As[ty * 4 + 1][kk];
            float a2 = As[ty * 4 + 2][kk];
            float a3 = As[ty * 4 + 3][kk];
            acc[0][0] += a0 * b4.x; acc[0][1] += a0 * b4.y; acc[0][2] += a0 * b4.z; acc[0][3] += a0 * b4.w;
            acc[1][0] += a1 * b4.x; acc[1][1] += a1 * b4.y; acc[1][2] += a1 * b4.z; acc[1][3] += a1 * b4.w;
            acc[2][0] += a2 * b4.x; acc[2][1] += a2 * b4.y; acc[2][2] += a2 * b4.z; acc[2][3] += a2 * b4.w;
            acc[3][0] += a3 * b4.x; acc[3][1] += a3 * b4.y; acc[3][2] += a3 * b4.z; acc[3][3] += a3 * b4.w;
        }
        __syncthreads();
    }
#pragma unroll
    for (int i = 0; i < 4; ++i) {
        int gr = row0 + ty * 4 + i;
        if (gr >= M) continue;
#pragma unroll
        for (int j = 0; j < 4; ++j) {
            int gc = col0 + tx * 4 + j;
            if (gc >= N) continue;
            float v = acc[i][j];
            if (bias) v += bias[gc];
            C[(size_t)gr * ldc + gc] = v;
        }
    }
}

// ================= fp32 GEMM (NT) small, for setup =================
__global__ __launch_bounds__(256) void gemm_nt(
    const float* __restrict__ A, const float* __restrict__ Bm, float* __restrict__ C,
    int N, int K, float alpha)
{
    __shared__ float As[64][65];
    __shared__ float Bs[64][65];
    const int tid = threadIdx.x;
    const int row0 = blockIdx.y * 64, col0 = blockIdx.x * 64;
    for (int idx = tid; idx < 64 * K; idx += 256) {
        int r = idx / K, c = idx % K;
        As[r][c] = A[(size_t)(row0 + r) * K + c];
        Bs[r][c] = Bm[(size_t)(col0 + r) * K + c];
    }
    __syncthreads();
    const int tx = tid & 15, ty = tid >> 4;
    float acc[4][4] = {};
    for (int c = 0; c < K; ++c) {
        float a[4], b[4];
#pragma unroll
        for (int i = 0; i < 4; ++i) a[i] = As[ty * 4 + i][c];
#pragma unroll
        for (int j = 0; j < 4; ++j) b[j] = Bs[tx * 4 + j][c];
#pragma unroll
        for (int i = 0; i < 4; ++i)
#pragma unroll
            for (int j = 0; j < 4; ++j) acc[i][j] += a[i] * b[j];
    }
#pragma unroll
    for (int i = 0; i < 4; ++i)
#pragma unroll
        for (int j = 0; j < 4; ++j)
            C[(size_t)(row0 + ty * 4 + i) * N + col0 + tx * 4 + j] = alpha * acc[i][j];
}

// ======= row softmax over 1024 cols; optional fp32 and/or bf16 outputs =======
__global__ __launch_bounds__(256) void row_softmax(
    const float* __restrict__ in, float* __restrict__ out32, int os32,
    bf16* __restrict__ out16, int os16, int relu)
{
    const float* rp = in + (size_t)blockIdx.x * N_;
    const int tid = threadIdx.x;
    float v[4];
#pragma unroll
    for (int j = 0; j < 4; ++j) {
        float x = rp[tid + 256 * j];
        if (relu) x = fmaxf(x, 0.f);
        v[j] = x;
    }
    float m = fmaxf(fmaxf(v[0], v[1]), fmaxf(v[2], v[3]));
#pragma unroll
    for (int off = 32; off > 0; off >>= 1) m = fmaxf(m, __shfl_xor(m, off));
    __shared__ float red[4], red2[4];
    int w = tid >> 6;
    if ((tid & 63) == 0) red[w] = m;
    __syncthreads();
    m = fmaxf(fmaxf(red[0], red[1]), fmaxf(red[2], red[3]));
    float s = 0.f;
#pragma unroll
    for (int j = 0; j < 4; ++j) { v[j] = __expf(v[j] - m); s += v[j]; }
#pragma unroll
    for (int off = 32; off > 0; off >>= 1) s += __shfl_xor(s, off);
    if ((tid & 63) == 0) red2[w] = s;
    __syncthreads();
    s = red2[0] + red2[1] + red2[2] + red2[3];
    float inv = 1.f / s;
#pragma unroll
    for (int j = 0; j < 4; ++j) {
        float r = v[j] * inv;
        if (out32) out32[(size_t)blockIdx.x * os32 + tid + 256 * j] = r;
        if (out16) out16[(size_t)blockIdx.x * os16 + tid + 256 * j] = __float2bfloat16(r);
    }
}

// ======= transpose 1024x1024 fp32 -> bf16 (out[r][c] = in[c][r]) =======
__global__ __launch_bounds__(256) void transpose_f2b(
    const float* __restrict__ in, bf16* __restrict__ out)
{
    __shared__ float t[64][65];
    const int cx = blockIdx.x, cy = blockIdx.y;
    const int tid = threadIdx.x;
#pragma unroll
    for (int k = 0; k < 16; ++k) {
        int idx = k * 256 + tid;
        int r = idx >> 6, c = idx & 63;
        t[r][c] = in[(size_t)(cy * 64 + r) * 1024 + cx * 64 + c];
    }
    __syncthreads();
#pragma unroll
    for (int k = 0; k < 16; ++k) {
        int idx = k * 256 + tid;
        int r = idx >> 6, c = idx & 63;
        out[(size_t)(cx * 64 + r) * 1024 + cy * 64 + c] = __float2bfloat16(t[c][r]);
    }
}

// ================= WgcT[(g*64+f)][e] = Wg[g][e][f], bf16 =================
__global__ __launch_bounds__(256) void wgct_kernel(const float* __restrict__ Wg,
                                                   bf16* __restrict__ WgcT)
{
    int i = blockIdx.x * 256 + threadIdx.x;  // 16384
    int g = i >> 12, e = (i >> 6) & 63, f = i & 63;
    WgcT[(((size_t)g * 64 + f) << 6) + e] = __float2bfloat16(Wg[i]);
}

// ====== Wvc1T[(kp*64+e)][f] = Wvc1[kp][f][e], bf16, padded to 256 rows ======
__global__ __launch_bounds__(256) void wvc1t_kernel(const float* __restrict__ Wvc1,
                                                    bf16* __restrict__ WT)
{
    int i = blockIdx.x * 256 + threadIdx.x;  // 256*64
    int row = i >> 6, f = i & 63;
    float v = 0.f;
    if (row < 192) { int kp = row >> 6, e = row & 63; v = Wvc1[kp * 4096 + f * 64 + e]; }
    WT[i] = __float2bfloat16(v);
}

// ================= fp32 -> bf16 convert =================
__global__ __launch_bounds__(256) void f2b_kernel(const float* __restrict__ in,
                                                  bf16* __restrict__ out, int n)
{
    int i = blockIdx.x * 256 + threadIdx.x;
    if (i < n) out[i] = __float2bfloat16(in[i]);
}

// ================= folded gate bias =================
__global__ __launch_bounds__(256) void bias_kernel(
    const float* __restrict__ bvz, const float* __restrict__ Wmz, const float* __restrict__ bmz,
    const float* __restrict__ Wgz, const float* __restrict__ bgz, float* __restrict__ bgconst)
{
    __shared__ float bconst[64];
    const int tid = threadIdx.x;
    if (tid < 64) {
        float s = bmz[tid];
        for (int kp = 0; kp < 3; ++kp)
            for (int f = 0; f < 64; ++f) s += bvz[f] * Wmz[kp * 4096 + f * 64 + tid];
        bconst[tid] = s;
    }
    __syncthreads();
    int g = tid >> 6, fo = tid & 63;
    float s = bgz[g * 64 + fo];
    for (int e = 0; e < 64; ++e) s += bconst[e] * Wgz[g * 4096 + e * 64 + fo];
    bgconst[tid] = s;
}

// ====== VcatT build for layer 0: VcatT[(l*16+b)*64+e][kp*1024+n], bf16 ======
__global__ __launch_bounds__(256) void vcat0T_kernel(
    const float* __restrict__ hist, const float* __restrict__ Wvc0,
    bf16* __restrict__ VcatT, int l0, int LC)
{
    __shared__ float xs[3][1024];
    __shared__ float Ws[576];
    const int lb = blockIdx.x;   // l*16+b
    const int l = lb >> 4, b = lb & 15;
    const int eq = blockIdx.y;   // e quarter
    const int tid = threadIdx.x;
    for (int i = tid; i < 576; i += 256) Ws[i] = Wvc0[i];
    const float* xp = hist + ((size_t)b * L_ + (l0 + l)) * N_ * 3;
    for (int i = tid; i < 3072; i += 256) xs[i % 3][i / 3] = xp[i];
    __syncthreads();
    bf16* outb = VcatT + (size_t)lb * 64 * 3072;
#pragma unroll
    for (int kp = 0; kp < 3; ++kp)
        for (int ei = 0; ei < 16; ++ei) {
            int e = eq * 16 + ei;
            float w0 = Ws[kp * 192 + e], w1 = Ws[kp * 192 + 64 + e], w2 = Ws[kp * 192 + 128 + e];
            bf16* rp = outb + (size_t)e * 3072 + kp * 1024;
#pragma unroll
            for (int q = 0; q < 4; ++q) {
                int n = q * 256 + tid;
                rp[n] = __float2bfloat16(fmaf(xs[0][n], w0, fmaf(xs[1][n], w1, xs[2][n] * w2)));
            }
        }
}

__device__ __forceinline__ void gload16(const bf16* g, bf16* l)
{
    __builtin_amdgcn_global_load_lds((const __attribute__((address_space(1))) void*)g,
                                     (__attribute__((address_space(3))) void*)l, 16, 0, 0);
}

// ================= bf16 MFMA GEMM (NT): C = A @ BT^T, 128^2 tile (K=64..1024) =================
template <int OUT_BF16, int REMAP>
__global__ __launch_bounds__(256) void gemm_mfma(
    const bf16* __restrict__ A, const bf16* __restrict__ BT, void* __restrict__ Cp,
    int M, int N, int K, int lda, int ldb, int ldc,
    const float* __restrict__ bias, int Nmask)
{
    __shared__ __align__(16) bf16 As[128 * 64];
    __shared__ __align__(16) bf16 Bs[128 * 64];
    const int tid = threadIdx.x;
    const int lane = tid & 63, w = tid >> 6;
    const int wr = w >> 1, wc = w & 1;
    const int row0 = blockIdx.y * 128, col0 = blockIdx.x * 128;
    if (REMAP) BT += (size_t)blockIdx.z * 64;

    f32x4 acc[4][4];
#pragma unroll
    for (int i = 0; i < 4; ++i)
#pragma unroll
        for (int j = 0; j < 4; ++j) acc[i][j] = (f32x4){0.f, 0.f, 0.f, 0.f};

    const int srow = w * 32 + (lane >> 3);
    const int scolsw = ((lane & 7) ^ (lane >> 3)) * 8;   // pre-swizzled k offset

    for (int k0 = 0; k0 < K; k0 += 64) {
#pragma unroll
        for (int i = 0; i < 4; ++i) {
            gload16(A + (size_t)(row0 + srow + i * 8) * lda + k0 + scolsw,
                    &As[(w * 32 + i * 8) * 64]);
            gload16(BT + (size_t)(col0 + srow + i * 8) * ldb + k0 + scolsw,
                    &Bs[(w * 32 + i * 8) * 64]);
        }
        __syncthreads();
#pragma unroll
        for (int kk = 0; kk < 64; kk += 32) {
            s16x8 af[4], bfr[4];
            const int ko = (kk + (lane >> 4) * 8) ^ ((lane & 7) << 3);
#pragma unroll
            for (int mi = 0; mi < 4; ++mi)
                af[mi] = *(const s16x8*)&As[(wr * 64 + mi * 16 + (lane & 15)) * 64 + ko];
#pragma unroll
            for (int ni = 0; ni < 4; ++ni)
                bfr[ni] = *(const s16x8*)&Bs[(wc * 64 + ni * 16 + (lane & 15)) * 64 + ko];
#pragma unroll
            for (int mi = 0; mi < 4; ++mi)
#pragma unroll
                for (int ni = 0; ni < 4; ++ni)
                    acc[mi][ni] = __builtin_amdgcn_mfma_f32_16x16x32_bf16(
                        af[mi], bfr[ni], acc[mi][ni], 0, 0, 0);
        }
        __syncthreads();
    }

    if (REMAP) {
        bf16* outb = (bf16*)Cp + (size_t)blockIdx.z * (64 * 3072);
#pragma unroll
        for (int mi = 0; mi < 4; ++mi) {
            const int gr = row0 + wr * 64 + mi * 16 + (lane >> 4) * 4;
#pragma unroll
            for (int ni = 0; ni < 4; ++ni) {
                const int gc = col0 + wc * 64 + ni * 16 + (lane & 15);
#pragma unroll
                for (int j = 0; j < 4; ++j) {
                    const int r = gr + j;
                    if (r >= Nmask) continue;
                    outb[(size_t)(r & 63) * 3072 + (r >> 6) * 1024 + gc] =
                        __float2bfloat16(acc[mi][ni][j]);
                }
            }
        }
        return;
    }

#pragma unroll
    for (int mi = 0; mi < 4; ++mi) {
        const int gr = row0 + wr * 64 + mi * 16 + (lane >> 4) * 4;
#pragma unroll
        for (int ni = 0; ni < 4; ++ni) {
            const int gc = col0 + wc * 64 + ni * 16 + (lane & 15);
            if (gc >= Nmask) continue;
            const float bb = bias ? bias[gc] : 0.f;
#pragma unroll
            for (int j = 0; j < 4; ++j) {
                float v = acc[mi][ni][j] + bb;
                if (OUT_BF16)
                    ((bf16*)Cp)[(size_t)(gr + j) * ldc + gc] = __float2bfloat16(v);
                else
                    ((float*)Cp)[(size_t)(gr + j) * ldc + gc] = v;
            }
        }
    }
}

// ====== pipelined bf16 MFMA GEMM (NT), 256x256 tile, BK=32, 4 LDS buffers ======
// C = A @ BT^T.  M = grid.y*256 (M%256==0), N%256==0, K%32==0, K>=64.
// 512 threads = 8 waves (2M x 4N), per-wave 128x64 output.
// Counted-vmcnt pipeline: stage tile t+2 into buf (t+2)%4 while computing buf t%4;
// per-tile boundary wait = vmcnt(4) (tile t+1's 4 loads stay in flight); never 0
// except at the last tile.  LDS swizzle: line = 2 M-rows (64 elems), 16B slot
// s XOR'd with (line&3); applied on global source (stage) and read offsets.
__global__ __launch_bounds__(512) void gemm_pipe(
    const bf16* __restrict__ A, const bf16* __restrict__ BT, bf16* __restrict__ C,
    int N, int K)
{
    __shared__ __align__(16) bf16 lds[4 * 16384];   // 128 KiB: buf = A(8192) + B(8192)
    const int tid = threadIdx.x;
    const int lane = tid & 63, w = tid >> 6;
    const int wm = w >> 2, wn = w & 3;
    const int row0 = blockIdx.y * 256, col0 = blockIdx.x * 256;

    // staging decode (2 calls per matrix per tile; call c: chunk q=c*8+w)
    int sm[2], sk[2], sl[2];
#pragma unroll
    for (int c = 0; c < 2; ++c) {
        int g = (c * 8 + w) * 64 + lane;      // 8-elem group id
        int l = g >> 3, rem = g & 7;
        int h = rem >> 2, sx = rem & 3;
        sm[c] = 2 * l + h;                    // source row within 256-tile
        sk[c] = (sx ^ (l & 3)) * 8;           // source k offset within 32
        sl[c] = (c * 8 + w) * 512;            // wave-uniform LDS elem base
    }
    // fragment read offsets (elems)
    int aoff[8], boff[4];
    const int fs = lane >> 4;                 // k-slot 0..3
#pragma unroll
    for (int mi = 0; mi < 8; ++mi) {
        int m = wm * 128 + mi * 16 + (lane & 15);
        aoff[mi] = (m >> 1) * 64 + (m & 1) * 32 + ((fs ^ ((m >> 1) & 3)) * 8);
    }
#pragma unroll
    for (int ni = 0; ni < 4; ++ni) {
        int n = wn * 64 + ni * 16 + (lane & 15);
        boff[ni] = 8192 + (n >> 1) * 64 + (n & 1) * 32 + ((fs ^ ((n >> 1) & 3)) * 8);
    }

    const bf16* Abase = A + (size_t)row0 * K;
    const bf16* Bbase = BT + (size_t)col0 * K;
    auto stageA = [&](int t) {
        bf16* dst = &lds[(t & 3) * 16384];
        const bf16* src = Abase + t * 32;
#pragma unroll
        for (int c = 0; c < 2; ++c)
            gload16(src + (size_t)sm[c] * K + sk[c], dst + sl[c]);
    };
    auto stageB = [&](int t) {
        bf16* dst = &lds[(t & 3) * 16384 + 8192];
        const bf16* src = Bbase + t * 32;
#pragma unroll
        for (int c = 0; c < 2; ++c)
            gload16(src + (size_t)sm[c] * K + sk[c], dst + sl[c]);
    };

    f32x4 acc[8][4];
#pragma unroll
    for (int i = 0; i < 8; ++i)
#pragma unroll
        for (int j = 0; j < 4; ++j) acc[i][j] = (f32x4){0.f, 0.f, 0.f, 0.f};

    const int NT = K >> 5;
    stageA(0); stageB(0); stageA(1); stageB(1);

    for (int t = 0; t < NT; ++t) {
        const bf16* buf = &lds[(t & 3) * 16384];
        if (t + 1 < NT) asm volatile("s_waitcnt vmcnt(4)" ::: "memory");
        else            asm volatile("s_waitcnt vmcnt(0)" ::: "memory");
        __builtin_amdgcn_sched_barrier(0);
        __builtin_amdgcn_s_barrier();
        // ---- phase 0: B frags + A frags mi 0-3, stage A(t+2) ----
        s16x8 bfr[4], af[4];
#pragma unroll
        for (int ni = 0; ni < 4; ++ni) bfr[ni] = *(const s16x8*)&buf[boff[ni]];
#pragma unroll
        for (int mi = 0; mi < 4; ++mi) af[mi] = *(const s16x8*)&buf[aoff[mi]];
        if (t + 2 < NT) stageA(t + 2);
        __builtin_amdgcn_s_barrier();
        __builtin_amdgcn_s_setprio(1);
#pragma unroll
        for (int mi = 0; mi < 4; ++mi)
#pragma unroll
            for (int ni = 0; ni < 4; ++ni)
                acc[mi][ni] = __builtin_amdgcn_mfma_f32_16x16x32_bf16(
                    af[mi], bfr[ni], acc[mi][ni], 0, 0, 0);
        __builtin_amdgcn_s_setprio(0);
        __builtin_amdgcn_s_barrier();
        // ---- phase 1: A frags mi 4-7, stage B(t+2) ----
        s16x8 ag[4];
#pragma unroll
        for (int mi = 0; mi < 4; ++mi) ag[mi] = *(const s16x8*)&buf[aoff[4 + mi]];
        if (t + 2 < NT) stageB(t + 2);
        __builtin_amdgcn_s_barrier();
        __builtin_amdgcn_s_setprio(1);
#pragma unroll
        for (int mi = 0; mi < 4; ++mi)
#pragma unroll
            for (int ni = 0; ni < 4; ++ni)
                acc[4 + mi][ni] = __builtin_amdgcn_mfma_f32_16x16x32_bf16(
                    ag[mi], bfr[ni], acc[4 + mi][ni], 0, 0, 0);
        __builtin_amdgcn_s_setprio(0);
    }

#pragma unroll
    for (int mi = 0; mi < 8; ++mi) {
        const int gr = row0 + wm * 128 + mi * 16 + (lane >> 4) * 4;
#pragma unroll
        for (int ni = 0; ni < 4; ++ni) {
            const int gc = col0 + wn * 64 + ni * 16 + (lane & 15);
#pragma unroll
            for (int j = 0; j < 4; ++j)
                C[(size_t)(gr + j) * N + gc] = __float2bfloat16(acc[mi][ni][j]);
        }
    }
}

// ========== fused gates GEMM (16x256,K=64 MFMA per step) + LSTM scan ==========
__global__ __launch_bounds__(256) void fused_gates_scan(
    const bf16* __restrict__ HG, const bf16* __restrict__ WgcT,
    const float* __restrict__ bgc, float* __restrict__ ct_buf,
    bf16* __restrict__ ht_out, float* __restrict__ htlast,
    int LC, int l0, int initct)
{
    __shared__ __align__(16) bf16 As[256 * 64];   // up to LC=16 staged HG rows
    __shared__ __align__(16) bf16 Bs[256 * 64];
    __shared__ float gbuf[16 * 260];   // padded rows: 260 floats
    __shared__ float bgs[256];
    const int tid = threadIdx.x;
    const int lane = tid & 63, w = tid >> 6;
    const int n = blockIdx.x;
    const int swz = ((lane & 7) ^ (lane >> 3)) * 8;
    const int l8 = (lane >> 3) * 64;

#pragma unroll
    for (int r = 0; r < 8; ++r)
        gload16(WgcT + r * 2048 + w * 512 + l8 + swz, &Bs[r * 2048 + w * 512]);
    const bf16* HGn = HG + (size_t)n * LC * 1024;
    const int totA = LC * 1024;
    for (int r = 0; r * 2048 < totA; ++r) {
        int seg = r * 2048 + w * 512;
        if (seg < totA) gload16(HGn + seg + l8 + swz, &As[seg]);
    }
    bgs[tid] = bgc[tid];
    __syncthreads();

    float ct[4];
    const size_t cbase = (size_t)n * 1024;
#pragma unroll
    for (int it = 0; it < 4; ++it)
        ct[it] = initct ? 0.f : ct_buf[cbase + it * 256 + tid];

    const int ar = (lane & 15);
    const int ak = (lane >> 4) * 8;
    const int kswz = (lane & 7) << 3;
    for (int l = 0; l < LC; ++l) {
        f32x4 acc[4];
#pragma unroll
        for (int ni = 0; ni < 4; ++ni) acc[ni] = (f32x4){0.f, 0.f, 0.f, 0.f};
#pragma unroll
        for (int kk = 0; kk < 64; kk += 32) {
            const int ko = (ak + kk) ^ kswz;
            s16x8 af = *(const s16x8*)&As[(l * 16 + ar) * 64 + ko];
#pragma unroll
            for (int ni = 0; ni < 4; ++ni) {
                s16x8 bf = *(const s16x8*)&Bs[(w * 64 + ni * 16 + ar) * 64 + ko];
                acc[ni] = __builtin_amdgcn_mfma_f32_16x16x32_bf16(af, bf, acc[ni], 0, 0, 0);
            }
        }
        __syncthreads();   // previous scan's gbuf reads complete
#pragma unroll
        for (int ni = 0; ni < 4; ++ni)
#pragma unroll
            for (int j = 0; j < 4; ++j)
                gbuf[((lane >> 4) * 4 + j) * 260 + w * 64 + ni * 16 + (lane & 15)] = acc[ni][j];
        __syncthreads();
        const size_t hbase = ((size_t)n * LC + l) * 1024;
        const bool last = (l0 + l == L_ - 1);
#pragma unroll
        for (int it = 0; it < 4; ++it) {
            const int flat = it * 256 + tid;
            const int bi = (flat >> 6) * 260 + (flat & 63);
            const int f = flat & 63;
            float xf = gbuf[bi] + bgs[f];
            float xi = gbuf[bi + 64] + bgs[64 + f];
            float xg = gbuf[bi + 128] + bgs[128 + f];
            float xo = gbuf[bi + 192] + bgs[192 + f];
            float fg = 1.f / (1.f + __expf(-xf));
            float ig = 1.f / (1.f + __expf(-xi));
            float gg = 2.f / (1.f + __expf(-2.f * xg)) - 1.f;
            float og = 1.f / (1.f + __expf(-xo));
            ct[it] = fg * ct[it] + ig * gg;
            float ht = og * (2.f / (1.f + __expf(-2.f * ct[it])) - 1.f);
            if (ht_out) ht_out[hbase + flat] = __float2bfloat16(ht);
            if (htlast && last) htlast[cbase + flat] = ht;
        }
    }
#pragma unroll
    for (int it = 0; it < 4; ++it)
        ct_buf[cbase + it * 256 + tid] = ct[it];
}

// ================= decoder =================
__global__ __launch_bounds__(256) void decoder_kernel(
    const float* __restrict__ h0, const float* __restrict__ h1,
    const float* __restrict__ Wdec, const float* __restrict__ bdec,
    const float* __restrict__ Wout, const float* __restrict__ bout,
    float* __restrict__ outp)
{
    __shared__ float Wd[12 * 2 * 64];
    __shared__ float Wo[144];
    __shared__ float bd[12], bo[12];
    const int tid = threadIdx.x;
    for (int i = tid; i < 12 * 2 * 64; i += 256) Wd[i] = Wdec[i];
    for (int i = tid; i < 144; i += 256) Wo[i] = Wout[i];
    if (tid < 12) { bd[tid] = bdec[tid]; bo[tid] = bout[tid]; }
    __syncthreads();
    const int gid = blockIdx.x * 256 + tid;   // b*1024 + n
    const int b = gid >> 10, n = gid & 1023;
    const float* h0r = h0 + ((size_t)n * 16 + b) * 64;
    const float* h1r = h1 + ((size_t)n * 16 + b) * 64;
    float dec[12];
#pragma unroll
    for (int o = 0; o < 12; ++o) dec[o] = bd[o];
    for (int e = 0; e < 64; ++e) {
        float v0 = h0r[e], v1 = h1r[e];
#pragma unroll
        for (int o = 0; o < 12; ++o) dec[o] += v0 * Wd[o * 128 + e] + v1 * Wd[o * 128 + 64 + e];
    }
#pragma unroll
    for (int o = 0; o < 12; ++o) {
        float s = bo[o];
#pragma unroll
        for (int p = 0; p < 12; ++p) s += Wo[o * 12 + p] * dec[p];
        outp[((size_t)b * 12 + o) * 1024 + n] = s;
    }
}

extern "C" void kernel_launch(void* const* d_in, const int* in_sizes, int n_in,
                              void* d_out, int out_size, void* d_ws, size_t ws_size,
                              hipStream_t stream)
{
    const float* hist = (const float*)d_in[0];
    const float* adj  = (const float*)d_in[1];
    const float* Wv0  = (const float*)d_in[2];
    const float* Wv1  = (const float*)d_in[3];
    const float* bv   = (const float*)d_in[4];
    const float* E    = (const float*)d_in[5];
    const float* Wq   = (const float*)d_in[6];
    const float* Wk   = (const float*)d_in[7];
    const float* Eg1  = (const float*)d_in[8];
    const float* Eg2  = (const float*)d_in[9];
    const float* Wmix = (const float*)d_in[10];
    const float* bmix = (const float*)d_in[11];
    const float* Wg   = (const float*)d_in[12];
    const float* bg   = (const float*)d_in[13];
    const float* Wdec = (const float*)d_in[14];
    const float* bdec = (const float*)d_in[15];
    const float* Wout = (const float*)d_in[16];
    const float* bout = (const float*)d_in[17];
    float* outp = (float*)d_out;
    (void)in_sizes; (void)n_in; (void)out_size;

    char* ws = (char*)d_ws;
    size_t off = 0;
    auto alloc = [&](size_t bytes) -> void* {
        void* p = (void*)(ws + off);
        off += (bytes + 255) & ~(size_t)255;
        return p;
    };
    bf16*  Mcatb0 = (bf16*)alloc((size_t)1024 * 3072 * 2);   // [M1|M2|attn] bf16
    bf16*  Mcatb1 = (bf16*)alloc((size_t)1024 * 3072 * 2);
    float* attnf  = (float*)alloc((size_t)1024 * 1024 * 4);
    bf16*  attnT  = (bf16*)alloc((size_t)1024 * 1024 * 2);
    bf16*  adjb   = (bf16*)alloc((size_t)1024 * 1024 * 2);
    bf16*  adpb   = (bf16*)alloc((size_t)1024 * 1024 * 2);
    float* qb     = (float*)alloc((size_t)1024 * 64 * 4);
    float* kb     = (float*)alloc((size_t)1024 * 64 * 4);
    float* logits = (float*)alloc((size_t)1024 * 1024 * 4);
    float* Wvc0   = (float*)alloc(3 * 3 * 64 * 4);           // [kp][c][e]
    float* Wvc1   = (float*)alloc(3 * 64 * 64 * 4);          // [kp][f][e]
    bf16*  Wvc1T  = (bf16*)alloc(256 * 64 * 2);
    bf16*  WgcT0  = (bf16*)alloc(256 * 64 * 2);
    bf16*  WgcT1  = (bf16*)alloc(256 * 64 * 2);
    float* bgc0   = (float*)alloc(256 * 4);
    float* bgc1   = (float*)alloc(256 * 4);
    float* ct0    = (float*)alloc((size_t)N_ * B_ * 64 * 4);
    float* ct1    = (float*)alloc((size_t)N_ * B_ * 64 * 4);
    float* hl0    = (float*)alloc((size_t)N_ * B_ * 64 * 4);
    float* hl1    = (float*)alloc((size_t)N_ * B_ * 64 * 4);
    size_t fixed = off;

    // per-LC-unit scratch: VcatT 6MiB + HG 2MiB + ht0c 2MiB = 10MiB
    static const int divs[] = {16, 12, 8, 6, 4, 2, 1};
    int LC = 1;
    for (int di = 0; di < 7; ++di) {
        if (fixed + (size_t)divs[di] * 10485760ull + 65536 <= ws_size) { LC = divs[di]; break; }
    }
    bf16*  VcatT = (bf16*)alloc((size_t)LC * 6291456ull);   // (LC*1024) x 3072
    bf16*  HG    = (bf16*)alloc((size_t)LC * 2097152ull);   // 1024 x (LC*1024)
    bf16*  ht0c  = (bf16*)alloc((size_t)LC * 2097152ull);   // Mrows x 64

    dim3 blk(256);
    bf16*  McatB[2] = {Mcatb0, Mcatb1};
    bf16*  WgcT[2] = {WgcT0, WgcT1};
    float* bgc[2] = {bgc0, bgc1};

    f2b_kernel<<<4096, blk, 0, stream>>>(adj, adjb, 1024 * 1024);
    for (int z = 0; z < 2; ++z) {
        const float* Ez = E + (size_t)z * N_ * 64;
        gemm_nn<<<dim3(1, 16), blk, 0, stream>>>(Ez, Wq + z * 4096, qb, 1024, 64, 64, 64, 64, 64, nullptr);
        gemm_nn<<<dim3(1, 16), blk, 0, stream>>>(Ez, Wk + z * 4096, kb, 1024, 64, 64, 64, 64, 64, nullptr);
        gemm_nt<<<dim3(16, 16), blk, 0, stream>>>(qb, kb, logits, 1024, 64, 0.125f);
        row_softmax<<<1024, blk, 0, stream>>>(logits, attnf, 1024, McatB[z] + 2048, 3072, 0);
        transpose_f2b<<<dim3(16, 16), blk, 0, stream>>>(attnf, attnT);
        gemm_nt<<<dim3(16, 16), blk, 0, stream>>>(Eg1 + z * 16384, Eg2 + z * 16384, logits, 1024, 16, 1.f);
        row_softmax<<<1024, blk, 0, stream>>>(logits, nullptr, 0, adpb, 1024, 1);
        gemm_mfma<1, 0><<<dim3(8, 8), blk, 0, stream>>>(adjb, attnT, McatB[z],
            1024, 1024, 1024, 1024, 1024, 3072, nullptr, 1024);
        gemm_mfma<1, 0><<<dim3(8, 8), blk, 0, stream>>>(adpb, attnT, McatB[z] + 1024,
            1024, 1024, 1024, 1024, 1024, 3072, nullptr, 1024);
        if (z == 0) {
            for (int kp = 0; kp < 3; ++kp)
                gemm_nn<<<dim3(1, 1), blk, 0, stream>>>(Wv0, Wmix + kp * 4096,
                    Wvc0 + kp * 3 * 64, 3, 64, 64, 64, 64, 64, nullptr);
        } else {
            for (int kp = 0; kp < 3; ++kp)
                gemm_nn<<<dim3(1, 1), blk, 0, stream>>>(Wv1, Wmix + 12288 + kp * 4096,
                    Wvc1 + kp * 4096, 64, 64, 64, 64, 64, 64, nullptr);
            wvc1t_kernel<<<64, blk, 0, stream>>>(Wvc1, Wvc1T);
        }
        wgct_kernel<<<64, blk, 0, stream>>>(Wg + z * 16384, WgcT[z]);
        bias_kernel<<<1, blk, 0, stream>>>(bv + z * 64, Wmix + z * 12288, bmix + z * 64,
            Wg + z * 16384, bg + z * 256, bgc[z]);
    }

    const int nch = L_ / LC;
    dim3 blk512(512);
    for (int c = 0; c < nch; ++c) {
        const int l0 = c * LC;
        // ---- layer 0 ----
        vcat0T_kernel<<<dim3(LC * 16, 4), blk, 0, stream>>>(hist, Wvc0, VcatT, l0, LC);
        gemm_pipe<<<dim3(LC * 4, 4), blk512, 0, stream>>>(Mcatb0, VcatT, HG,
            LC * 1024, 3072);
        fused_gates_scan<<<1024, blk, 0, stream>>>(HG, WgcT0, bgc0, ct0,
            ht0c, hl0, LC, l0, c == 0);
        // ---- layer 1: V build straight into VcatT (REMAP epilogue) ----
        gemm_mfma<1, 1><<<dim3(8, 2, LC * 16), blk, 0, stream>>>(Wvc1T, ht0c, VcatT,
            256, 1024, 64, 64, LC * 1024, 0, nullptr, 192);
        gemm_pipe<<<dim3(LC * 4, 4), blk512, 0, stream>>>(Mcatb1, VcatT, HG,
            LC * 1024, 3072);
        fused_gates_scan<<<1024, blk, 0, stream>>>(HG, WgcT1, bgc1, ct1,
            nullptr, hl1, LC, l0, c == 0);
    }
    decoder_kernel<<<64, blk, 0, stream>>>(hl0, hl1, Wdec, bdec, Wout, bout, outp);
}

// Round 6
// 2172.415 us; speedup vs baseline: 1.2612x; 1.2612x over previous
//
#include <hip/hip_runtime.h>
#include <hip/hip_bf16.h>

#define B_ 16
#define L_ 96
#define N_ 1024
#define EMB_ 64

typedef __hip_bfloat16 bf16;
typedef __attribute__((ext_vector_type(4))) float f32x4;
typedef __attribute__((ext_vector_type(8))) short s16x8;

// ================= fp32 GEMM (NN), small setup mats only =================
__global__ __launch_bounds__(256) void gemm_nn(
    const float* __restrict__ A, const float* __restrict__ Bm, float* __restrict__ C,
    int M, int N, int K, int lda, int ldb, int ldc, const float* __restrict__ bias)
{
    __shared__ float As[64][17];
    __shared__ __align__(16) float Bs[16][64];
    const int tid = threadIdx.x;
    const int tx = tid & 15, ty = tid >> 4;
    const int row0 = blockIdx.y * 64, col0 = blockIdx.x * 64;
    float acc[4][4] = {};
    const int ak = tid & 15, ar = tid >> 4;
    const int bc = tid & 63, bk = tid >> 6;
    for (int k0 = 0; k0 < K; k0 += 16) {
#pragma unroll
        for (int i = 0; i < 4; ++i) {
            int r = ar + i * 16;
            int gr = row0 + r, gk = k0 + ak;
            As[r][ak] = (gr < M && gk < K) ? A[(size_t)gr * lda + gk] : 0.f;
        }
#pragma unroll
        for (int i = 0; i < 4; ++i) {
            int kk = bk + i * 4;
            int gk = k0 + kk, gc = col0 + bc;
            Bs[kk][bc] = (gk < K && gc < N) ? Bm[(size_t)gk * ldb + gc] : 0.f;
        }
        __syncthreads();
#pragma unroll
        for (int kk = 0; kk < 16; ++kk) {
            float4 b4 = *reinterpret_cast<const float4*>(&Bs[kk][tx * 4]);
            float a0 = As[ty * 4 + 0][kk];
            float a1 = As[ty * 4 + 1][kk];
            float a2 = As[ty * 4 + 2][kk];
            float a3 = As[ty * 4 + 3][kk];
            acc[0][0] += a0 * b4.x; acc[0][1] += a0 * b4.y; acc[0][2] += a0 * b4.z; acc[0][3] += a0 * b4.w;
            acc[1][0] += a1 * b4.x; acc[1][1] += a1 * b4.y; acc[1][2] += a1 * b4.z; acc[1][3] += a1 * b4.w;
            acc[2][0] += a2 * b4.x; acc[2][1] += a2 * b4.y; acc[2][2] += a2 * b4.z; acc[2][3] += a2 * b4.w;
            acc[3][0] += a3 * b4.x; acc[3][1] += a3 * b4.y; acc[3][2] += a3 * b4.z; acc[3][3] += a3 * b4.w;
        }
        __syncthreads();
    }
#pragma unroll
    for (int i = 0; i < 4; ++i) {
        int gr = row0 + ty * 4 + i;
        if (gr >= M) continue;
#pragma unroll
        for (int j = 0; j < 4; ++j) {
            int gc = col0 + tx * 4 + j;
            if (gc >= N) continue;
            float v = acc[i][j];
            if (bias) v += bias[gc];
            C[(size_t)gr * ldc + gc] = v;
        }
    }
}

// ================= fp32 GEMM (NT) small, for setup =================
__global__ __launch_bounds__(256) void gemm_nt(
    const float* __restrict__ A, const float* __restrict__ Bm, float* __restrict__ C,
    int N, int K, float alpha)
{
    __shared__ float As[64][65];
    __shared__ float Bs[64][65];
    const int tid = threadIdx.x;
    const int row0 = blockIdx.y * 64, col0 = blockIdx.x * 64;
    for (int idx = tid; idx < 64 * K; idx += 256) {
        int r = idx / K, c = idx % K;
        As[r][c] = A[(size_t)(row0 + r) * K + c];
        Bs[r][c] = Bm[(size_t)(col0 + r) * K + c];
    }
    __syncthreads();
    const int tx = tid & 15, ty = tid >> 4;
    float acc[4][4] = {};
    for (int c = 0; c < K; ++c) {
        float a[4], b[4];
#pragma unroll
        for (int i = 0; i < 4; ++i) a[i] = As[ty * 4 + i][c];
#pragma unroll
        for (int j = 0; j < 4; ++j) b[j] = Bs[tx * 4 + j][c];
#pragma unroll
        for (int i = 0; i < 4; ++i)
#pragma unroll
            for (int j = 0; j < 4; ++j) acc[i][j] += a[i] * b[j];
    }
#pragma unroll
    for (int i = 0; i < 4; ++i)
#pragma unroll
        for (int j = 0; j < 4; ++j)
            C[(size_t)(row0 + ty * 4 + i) * N + col0 + tx * 4 + j] = alpha * acc[i][j];
}

// ======= row softmax over 1024 cols; optional fp32 and/or bf16 outputs =======
__global__ __launch_bounds__(256) void row_softmax(
    const float* __restrict__ in, float* __restrict__ out32, int os32,
    bf16* __restrict__ out16, int os16, int relu)
{
    const float* rp = in + (size_t)blockIdx.x * N_;
    const int tid = threadIdx.x;
    float v[4];
#pragma unroll
    for (int j = 0; j < 4; ++j) {
        float x = rp[tid + 256 * j];
        if (relu) x = fmaxf(x, 0.f);
        v[j] = x;
    }
    float m = fmaxf(fmaxf(v[0], v[1]), fmaxf(v[2], v[3]));
#pragma unroll
    for (int off = 32; off > 0; off >>= 1) m = fmaxf(m, __shfl_xor(m, off));
    __shared__ float red[4], red2[4];
    int w = tid >> 6;
    if ((tid & 63) == 0) red[w] = m;
    __syncthreads();
    m = fmaxf(fmaxf(red[0], red[1]), fmaxf(red[2], red[3]));
    float s = 0.f;
#pragma unroll
    for (int j = 0; j < 4; ++j) { v[j] = __expf(v[j] - m); s += v[j]; }
#pragma unroll
    for (int off = 32; off > 0; off >>= 1) s += __shfl_xor(s, off);
    if ((tid & 63) == 0) red2[w] = s;
    __syncthreads();
    s = red2[0] + red2[1] + red2[2] + red2[3];
    float inv = 1.f / s;
#pragma unroll
    for (int j = 0; j < 4; ++j) {
        float r = v[j] * inv;
        if (out32) out32[(size_t)blockIdx.x * os32 + tid + 256 * j] = r;
        if (out16) out16[(size_t)blockIdx.x * os16 + tid + 256 * j] = __float2bfloat16(r);
    }
}

// ======= transpose 1024x1024 fp32 -> bf16 (out[r][c] = in[c][r]) =======
__global__ __launch_bounds__(256) void transpose_f2b(
    const float* __restrict__ in, bf16* __restrict__ out)
{
    __shared__ float t[64][65];
    const int cx = blockIdx.x, cy = blockIdx.y;
    const int tid = threadIdx.x;
#pragma unroll
    for (int k = 0; k < 16; ++k) {
        int idx = k * 256 + tid;
        int r = idx >> 6, c = idx & 63;
        t[r][c] = in[(size_t)(cy * 64 + r) * 1024 + cx * 64 + c];
    }
    __syncthreads();
#pragma unroll
    for (int k = 0; k < 16; ++k) {
        int idx = k * 256 + tid;
        int r = idx >> 6, c = idx & 63;
        out[(size_t)(cx * 64 + r) * 1024 + cy * 64 + c] = __float2bfloat16(t[c][r]);
    }
}

// ================= WgcT[(g*64+f)][e] = Wg[g][e][f], bf16 =================
__global__ __launch_bounds__(256) void wgct_kernel(const float* __restrict__ Wg,
                                                   bf16* __restrict__ WgcT)
{
    int i = blockIdx.x * 256 + threadIdx.x;  // 16384
    int g = i >> 12, e = (i >> 6) & 63, f = i & 63;
    WgcT[(((size_t)g * 64 + f) << 6) + e] = __float2bfloat16(Wg[i]);
}

// ====== Wvc1T[(kp*64+e)][f] = Wvc1[kp][f][e], bf16, padded to 256 rows ======
__global__ __launch_bounds__(256) void wvc1t_kernel(const float* __restrict__ Wvc1,
                                                    bf16* __restrict__ WT)
{
    int i = blockIdx.x * 256 + threadIdx.x;  // 256*64
    int row = i >> 6, f = i & 63;
    float v = 0.f;
    if (row < 192) { int kp = row >> 6, e = row & 63; v = Wvc1[kp * 4096 + f * 64 + e]; }
    WT[i] = __float2bfloat16(v);
}

// ================= fp32 -> bf16 convert =================
__global__ __launch_bounds__(256) void f2b_kernel(const float* __restrict__ in,
                                                  bf16* __restrict__ out, int n)
{
    int i = blockIdx.x * 256 + threadIdx.x;
    if (i < n) out[i] = __float2bfloat16(in[i]);
}

// ================= folded gate bias =================
__global__ __launch_bounds__(256) void bias_kernel(
    const float* __restrict__ bvz, const float* __restrict__ Wmz, const float* __restrict__ bmz,
    const float* __restrict__ Wgz, const float* __restrict__ bgz, float* __restrict__ bgconst)
{
    __shared__ float bconst[64];
    const int tid = threadIdx.x;
    if (tid < 64) {
        float s = bmz[tid];
        for (int kp = 0; kp < 3; ++kp)
            for (int f = 0; f < 64; ++f) s += bvz[f] * Wmz[kp * 4096 + f * 64 + tid];
        bconst[tid] = s;
    }
    __syncthreads();
    int g = tid >> 6, fo = tid & 63;
    float s = bgz[g * 64 + fo];
    for (int e = 0; e < 64; ++e) s += bconst[e] * Wgz[g * 4096 + e * 64 + fo];
    bgconst[tid] = s;
}

// ====== VcatT build for layer 0: VcatT[(l*16+b)*64+e][kp*1024+n], bf16 ======
__global__ __launch_bounds__(256) void vcat0T_kernel(
    const float* __restrict__ hist, const float* __restrict__ Wvc0,
    bf16* __restrict__ VcatT, int l0, int LC)
{
    __shared__ float xs[3][1024];
    __shared__ float Ws[576];
    const int lb = blockIdx.x;   // l*16+b
    const int l = lb >> 4, b = lb & 15;
    const int eq = blockIdx.y;   // e quarter
    const int tid = threadIdx.x;
    for (int i = tid; i < 576; i += 256) Ws[i] = Wvc0[i];
    const float* xp = hist + ((size_t)b * L_ + (l0 + l)) * N_ * 3;
    for (int i = tid; i < 3072; i += 256) xs[i % 3][i / 3] = xp[i];
    __syncthreads();
    bf16* outb = VcatT + (size_t)lb * 64 * 3072;
#pragma unroll
    for (int kp = 0; kp < 3; ++kp)
        for (int ei = 0; ei < 16; ++ei) {
            int e = eq * 16 + ei;
            float w0 = Ws[kp * 192 + e], w1 = Ws[kp * 192 + 64 + e], w2 = Ws[kp * 192 + 128 + e];
            bf16* rp = outb + (size_t)e * 3072 + kp * 1024;
#pragma unroll
            for (int q = 0; q < 4; ++q) {
                int n = q * 256 + tid;
                rp[n] = __float2bfloat16(fmaf(xs[0][n], w0, fmaf(xs[1][n], w1, xs[2][n] * w2)));
            }
        }
}

__device__ __forceinline__ void gload16(const bf16* g, bf16* l)
{
    __builtin_amdgcn_global_load_lds((const __attribute__((address_space(1))) void*)g,
                                     (__attribute__((address_space(3))) void*)l, 16, 0, 0);
}

// ================= bf16 MFMA GEMM (NT): C = A @ BT^T, 128^2 tile (K=64..1024) =================
template <int OUT_BF16, int REMAP>
__global__ __launch_bounds__(256) void gemm_mfma(
    const bf16* __restrict__ A, const bf16* __restrict__ BT, void* __restrict__ Cp,
    int M, int N, int K, int lda, int ldb, int ldc,
    const float* __restrict__ bias, int Nmask)
{
    __shared__ __align__(16) bf16 As[128 * 64];
    __shared__ __align__(16) bf16 Bs[128 * 64];
    const int tid = threadIdx.x;
    const int lane = tid & 63, w = tid >> 6;
    const int wr = w >> 1, wc = w & 1;
    const int row0 = blockIdx.y * 128, col0 = blockIdx.x * 128;
    if (REMAP) BT += (size_t)blockIdx.z * 64;

    f32x4 acc[4][4];
#pragma unroll
    for (int i = 0; i < 4; ++i)
#pragma unroll
        for (int j = 0; j < 4; ++j) acc[i][j] = (f32x4){0.f, 0.f, 0.f, 0.f};

    const int srow = w * 32 + (lane >> 3);
    const int scolsw = ((lane & 7) ^ (lane >> 3)) * 8;   // pre-swizzled k offset

    for (int k0 = 0; k0 < K; k0 += 64) {
#pragma unroll
        for (int i = 0; i < 4; ++i) {
            gload16(A + (size_t)(row0 + srow + i * 8) * lda + k0 + scolsw,
                    &As[(w * 32 + i * 8) * 64]);
            gload16(BT + (size_t)(col0 + srow + i * 8) * ldb + k0 + scolsw,
                    &Bs[(w * 32 + i * 8) * 64]);
        }
        __syncthreads();
#pragma unroll
        for (int kk = 0; kk < 64; kk += 32) {
            s16x8 af[4], bfr[4];
            const int ko = (kk + (lane >> 4) * 8) ^ ((lane & 7) << 3);
#pragma unroll
            for (int mi = 0; mi < 4; ++mi)
                af[mi] = *(const s16x8*)&As[(wr * 64 + mi * 16 + (lane & 15)) * 64 + ko];
#pragma unroll
            for (int ni = 0; ni < 4; ++ni)
                bfr[ni] = *(const s16x8*)&Bs[(wc * 64 + ni * 16 + (lane & 15)) * 64 + ko];
#pragma unroll
            for (int mi = 0; mi < 4; ++mi)
#pragma unroll
                for (int ni = 0; ni < 4; ++ni)
                    acc[mi][ni] = __builtin_amdgcn_mfma_f32_16x16x32_bf16(
                        af[mi], bfr[ni], acc[mi][ni], 0, 0, 0);
        }
        __syncthreads();
    }

    if (REMAP) {
        bf16* outb = (bf16*)Cp + (size_t)blockIdx.z * (64 * 3072);
#pragma unroll
        for (int mi = 0; mi < 4; ++mi) {
            const int gr = row0 + wr * 64 + mi * 16 + (lane >> 4) * 4;
#pragma unroll
            for (int ni = 0; ni < 4; ++ni) {
                const int gc = col0 + wc * 64 + ni * 16 + (lane & 15);
#pragma unroll
                for (int j = 0; j < 4; ++j) {
                    const int r = gr + j;
                    if (r >= Nmask) continue;
                    outb[(size_t)(r & 63) * 3072 + (r >> 6) * 1024 + gc] =
                        __float2bfloat16(acc[mi][ni][j]);
                }
            }
        }
        return;
    }

#pragma unroll
    for (int mi = 0; mi < 4; ++mi) {
        const int gr = row0 + wr * 64 + mi * 16 + (lane >> 4) * 4;
#pragma unroll
        for (int ni = 0; ni < 4; ++ni) {
            const int gc = col0 + wc * 64 + ni * 16 + (lane & 15);
            if (gc >= Nmask) continue;
            const float bb = bias ? bias[gc] : 0.f;
#pragma unroll
            for (int j = 0; j < 4; ++j) {
                float v = acc[mi][ni][j] + bb;
                if (OUT_BF16)
                    ((bf16*)Cp)[(size_t)(gr + j) * ldc + gc] = __float2bfloat16(v);
                else
                    ((float*)Cp)[(size_t)(gr + j) * ldc + gc] = v;
            }
        }
    }
}

// ====== pipelined bf16 MFMA GEMM (NT), 256x256 tile, BK=32, 4 LDS buffers ======
__global__ __launch_bounds__(512) void gemm_pipe(
    const bf16* __restrict__ A, const bf16* __restrict__ BT, bf16* __restrict__ C,
    int N, int K)
{
    __shared__ __align__(16) bf16 lds[4 * 16384];   // 128 KiB: buf = A(8192) + B(8192)
    const int tid = threadIdx.x;
    const int lane = tid & 63, w = tid >> 6;
    const int wm = w >> 2, wn = w & 3;
    const int row0 = blockIdx.y * 256, col0 = blockIdx.x * 256;

    int sm[2], sk[2], sl[2];
#pragma unroll
    for (int c = 0; c < 2; ++c) {
        int g = (c * 8 + w) * 64 + lane;
        int l = g >> 3, rem = g & 7;
        int h = rem >> 2, sx = rem & 3;
        sm[c] = 2 * l + h;
        sk[c] = (sx ^ (l & 3)) * 8;
        sl[c] = (c * 8 + w) * 512;
    }
    int aoff[8], boff[4];
    const int fs = lane >> 4;
#pragma unroll
    for (int mi = 0; mi < 8; ++mi) {
        int m = wm * 128 + mi * 16 + (lane & 15);
        aoff[mi] = (m >> 1) * 64 + (m & 1) * 32 + ((fs ^ ((m >> 1) & 3)) * 8);
    }
#pragma unroll
    for (int ni = 0; ni < 4; ++ni) {
        int n = wn * 64 + ni * 16 + (lane & 15);
        boff[ni] = 8192 + (n >> 1) * 64 + (n & 1) * 32 + ((fs ^ ((n >> 1) & 3)) * 8);
    }

    const bf16* Abase = A + (size_t)row0 * K;
    const bf16* Bbase = BT + (size_t)col0 * K;
    auto stageA = [&](int t) {
        bf16* dst = &lds[(t & 3) * 16384];
        const bf16* src = Abase + t * 32;
#pragma unroll
        for (int c = 0; c < 2; ++c)
            gload16(src + (size_t)sm[c] * K + sk[c], dst + sl[c]);
    };
    auto stageB = [&](int t) {
        bf16* dst = &lds[(t & 3) * 16384 + 8192];
        const bf16* src = Bbase + t * 32;
#pragma unroll
        for (int c = 0; c < 2; ++c)
            gload16(src + (size_t)sm[c] * K + sk[c], dst + sl[c]);
    };

    f32x4 acc[8][4];
#pragma unroll
    for (int i = 0; i < 8; ++i)
#pragma unroll
        for (int j = 0; j < 4; ++j) acc[i][j] = (f32x4){0.f, 0.f, 0.f, 0.f};

    const int NT = K >> 5;
    stageA(0); stageB(0); stageA(1); stageB(1);

    for (int t = 0; t < NT; ++t) {
        const bf16* buf = &lds[(t & 3) * 16384];
        if (t + 1 < NT) asm volatile("s_waitcnt vmcnt(4)" ::: "memory");
        else            asm volatile("s_waitcnt vmcnt(0)" ::: "memory");
        __builtin_amdgcn_sched_barrier(0);
        __builtin_amdgcn_s_barrier();
        s16x8 bfr[4], af[4];
#pragma unroll
        for (int ni = 0; ni < 4; ++ni) bfr[ni] = *(const s16x8*)&buf[boff[ni]];
#pragma unroll
        for (int mi = 0; mi < 4; ++mi) af[mi] = *(const s16x8*)&buf[aoff[mi]];
        if (t + 2 < NT) stageA(t + 2);
        __builtin_amdgcn_s_barrier();
        __builtin_amdgcn_s_setprio(1);
#pragma unroll
        for (int mi = 0; mi < 4; ++mi)
#pragma unroll
            for (int ni = 0; ni < 4; ++ni)
                acc[mi][ni] = __builtin_amdgcn_mfma_f32_16x16x32_bf16(
                    af[mi], bfr[ni], acc[mi][ni], 0, 0, 0);
        __builtin_amdgcn_s_setprio(0);
        __builtin_amdgcn_s_barrier();
        s16x8 ag[4];
#pragma unroll
        for (int mi = 0; mi < 4; ++mi) ag[mi] = *(const s16x8*)&buf[aoff[4 + mi]];
        if (t + 2 < NT) stageB(t + 2);
        __builtin_amdgcn_s_barrier();
        __builtin_amdgcn_s_setprio(1);
#pragma unroll
        for (int mi = 0; mi < 4; ++mi)
#pragma unroll
            for (int ni = 0; ni < 4; ++ni)
                acc[4 + mi][ni] = __builtin_amdgcn_mfma_f32_16x16x32_bf16(
                    ag[mi], bfr[ni], acc[4 + mi][ni], 0, 0, 0);
        __builtin_amdgcn_s_setprio(0);
    }

#pragma unroll
    for (int mi = 0; mi < 8; ++mi) {
        const int gr = row0 + wm * 128 + mi * 16 + (lane >> 4) * 4;
#pragma unroll
        for (int ni = 0; ni < 4; ++ni) {
            const int gc = col0 + wn * 64 + ni * 16 + (lane & 15);
#pragma unroll
            for (int j = 0; j < 4; ++j)
                C[(size_t)(gr + j) * N + gc] = __float2bfloat16(acc[mi][ni][j]);
        }
    }
}

// ========== fused gates GEMM + IN-REGISTER LSTM scan ==========
// Block = one node n (1024 blocks). Gate-major C mapping: acc[ni][j] = gate ni
// for b = (lane>>4)*4+j, f = w*16+(lane&15). All 4 gates lane-local -> no gbuf,
// no barriers in the l-loop. A frags read direct from global (coalesced 2KB),
// prefetched one step ahead. LDS = WgcT (32KB, swizzled) + bias -> 4 blocks/CU.
__global__ __launch_bounds__(256, 4) void fused_gates_scan(
    const bf16* __restrict__ HG, const bf16* __restrict__ WgcT,
    const float* __restrict__ bgc, float* __restrict__ ct_buf,
    bf16* __restrict__ ht_out, float* __restrict__ htlast,
    int LC, int l0, int initct)
{
    __shared__ __align__(16) bf16 Bs[256 * 64];
    __shared__ float bgs[256];
    const int tid = threadIdx.x;
    const int lane = tid & 63, w = tid >> 6;
    const int n = blockIdx.x;
    const int swz = ((lane & 7) ^ (lane >> 3)) * 8;
    const int l8 = (lane >> 3) * 64;

#pragma unroll
    for (int r = 0; r < 8; ++r)
        gload16(WgcT + r * 2048 + w * 512 + l8 + swz, &Bs[r * 2048 + w * 512]);
    bgs[tid] = bgc[tid];
    __syncthreads();

    const int ar = lane & 15;
    const int ak = (lane >> 4) * 8;
    const int kswz = (lane & 7) << 3;
    const int f = w * 16 + ar;          // this lane's gate column f
    const int r0 = (lane >> 4) * 4;     // this lane's first b row
    const float bgf = bgs[f], bgi = bgs[64 + f], bgg = bgs[128 + f], bgo = bgs[192 + f];

    float ct[4];
    const size_t cbase = (size_t)n * 1024;
#pragma unroll
    for (int j = 0; j < 4; ++j)
        ct[j] = initct ? 0.f : ct_buf[cbase + (size_t)(r0 + j) * 64 + f];

    const bf16* HGn = HG + (size_t)n * LC * 1024;
    s16x8 a0 = *(const s16x8*)&HGn[ar * 64 + ak];
    s16x8 a1 = *(const s16x8*)&HGn[ar * 64 + ak + 32];

    for (int l = 0; l < LC; ++l) {
        // prefetch next step's A fragments (wave-uniform branch)
        s16x8 p0 = a0, p1 = a1;
        if (l + 1 < LC) {
            p0 = *(const s16x8*)&HGn[((l + 1) * 16 + ar) * 64 + ak];
            p1 = *(const s16x8*)&HGn[((l + 1) * 16 + ar) * 64 + ak + 32];
        }
        f32x4 acc[4];
#pragma unroll
        for (int ni = 0; ni < 4; ++ni) acc[ni] = (f32x4){0.f, 0.f, 0.f, 0.f};
#pragma unroll
        for (int ni = 0; ni < 4; ++ni) {
            s16x8 bf = *(const s16x8*)&Bs[(ni * 64 + w * 16 + ar) * 64 + (ak ^ kswz)];
            acc[ni] = __builtin_amdgcn_mfma_f32_16x16x32_bf16(a0, bf, acc[ni], 0, 0, 0);
        }
#pragma unroll
        for (int ni = 0; ni < 4; ++ni) {
            s16x8 bf = *(const s16x8*)&Bs[(ni * 64 + w * 16 + ar) * 64 + ((ak + 32) ^ kswz)];
            acc[ni] = __builtin_amdgcn_mfma_f32_16x16x32_bf16(a1, bf, acc[ni], 0, 0, 0);
        }
        const size_t hbase = ((size_t)n * LC + l) * 1024;
        const bool last = (l0 + l == L_ - 1);
#pragma unroll
        for (int j = 0; j < 4; ++j) {
            float xf = acc[0][j] + bgf;
            float xi = acc[1][j] + bgi;
            float xg = acc[2][j] + bgg;
            float xo = acc[3][j] + bgo;
            float fg = 1.f / (1.f + __expf(-xf));
            float ig = 1.f / (1.f + __expf(-xi));
            float gg = 2.f / (1.f + __expf(-2.f * xg)) - 1.f;
            float og = 1.f / (1.f + __expf(-xo));
            ct[j] = fg * ct[j] + ig * gg;
            float ht = og * (2.f / (1.f + __expf(-2.f * ct[j])) - 1.f);
            if (ht_out) ht_out[hbase + (size_t)(r0 + j) * 64 + f] = __float2bfloat16(ht);
            if (htlast && last) htlast[cbase + (size_t)(r0 + j) * 64 + f] = ht;
        }
        a0 = p0; a1 = p1;
    }
#pragma unroll
    for (int j = 0; j < 4; ++j)
        ct_buf[cbase + (size_t)(r0 + j) * 64 + f] = ct[j];
}

// ================= decoder =================
__global__ __launch_bounds__(256) void decoder_kernel(
    const float* __restrict__ h0, const float* __restrict__ h1,
    const float* __restrict__ Wdec, const float* __restrict__ bdec,
    const float* __restrict__ Wout, const float* __restrict__ bout,
    float* __restrict__ outp)
{
    __shared__ float Wd[12 * 2 * 64];
    __shared__ float Wo[144];
    __shared__ float bd[12], bo[12];
    const int tid = threadIdx.x;
    for (int i = tid; i < 12 * 2 * 64; i += 256) Wd[i] = Wdec[i];
    for (int i = tid; i < 144; i += 256) Wo[i] = Wout[i];
    if (tid < 12) { bd[tid] = bdec[tid]; bo[tid] = bout[tid]; }
    __syncthreads();
    const int gid = blockIdx.x * 256 + tid;   // b*1024 + n
    const int b = gid >> 10, n = gid & 1023;
    const float* h0r = h0 + ((size_t)n * 16 + b) * 64;
    const float* h1r = h1 + ((size_t)n * 16 + b) * 64;
    float dec[12];
#pragma unroll
    for (int o = 0; o < 12; ++o) dec[o] = bd[o];
    for (int e = 0; e < 64; ++e) {
        float v0 = h0r[e], v1 = h1r[e];
#pragma unroll
        for (int o = 0; o < 12; ++o) dec[o] += v0 * Wd[o * 128 + e] + v1 * Wd[o * 128 + 64 + e];
    }
#pragma unroll
    for (int o = 0; o < 12; ++o) {
        float s = bo[o];
#pragma unroll
        for (int p = 0; p < 12; ++p) s += Wo[o * 12 + p] * dec[p];
        outp[((size_t)b * 12 + o) * 1024 + n] = s;
    }
}

extern "C" void kernel_launch(void* const* d_in, const int* in_sizes, int n_in,
                              void* d_out, int out_size, void* d_ws, size_t ws_size,
                              hipStream_t stream)
{
    const float* hist = (const float*)d_in[0];
    const float* adj  = (const float*)d_in[1];
    const float* Wv0  = (const float*)d_in[2];
    const float* Wv1  = (const float*)d_in[3];
    const float* bv   = (const float*)d_in[4];
    const float* E    = (const float*)d_in[5];
    const float* Wq   = (const float*)d_in[6];
    const float* Wk   = (const float*)d_in[7];
    const float* Eg1  = (const float*)d_in[8];
    const float* Eg2  = (const float*)d_in[9];
    const float* Wmix = (const float*)d_in[10];
    const float* bmix = (const float*)d_in[11];
    const float* Wg   = (const float*)d_in[12];
    const float* bg   = (const float*)d_in[13];
    const float* Wdec = (const float*)d_in[14];
    const float* bdec = (const float*)d_in[15];
    const float* Wout = (const float*)d_in[16];
    const float* bout = (const float*)d_in[17];
    float* outp = (float*)d_out;
    (void)in_sizes; (void)n_in; (void)out_size;

    char* ws = (char*)d_ws;
    size_t off = 0;
    auto alloc = [&](size_t bytes) -> void* {
        void* p = (void*)(ws + off);
        off += (bytes + 255) & ~(size_t)255;
        return p;
    };
    bf16*  Mcatb0 = (bf16*)alloc((size_t)1024 * 3072 * 2);   // [M1|M2|attn] bf16
    bf16*  Mcatb1 = (bf16*)alloc((size_t)1024 * 3072 * 2);
    float* attnf  = (float*)alloc((size_t)1024 * 1024 * 4);
    bf16*  attnT  = (bf16*)alloc((size_t)1024 * 1024 * 2);
    bf16*  adjb   = (bf16*)alloc((size_t)1024 * 1024 * 2);
    bf16*  adpb   = (bf16*)alloc((size_t)1024 * 1024 * 2);
    float* qb     = (float*)alloc((size_t)1024 * 64 * 4);
    float* kb     = (float*)alloc((size_t)1024 * 64 * 4);
    float* logits = (float*)alloc((size_t)1024 * 1024 * 4);
    float* Wvc0   = (float*)alloc(3 * 3 * 64 * 4);           // [kp][c][e]
    float* Wvc1   = (float*)alloc(3 * 64 * 64 * 4);          // [kp][f][e]
    bf16*  Wvc1T  = (bf16*)alloc(256 * 64 * 2);
    bf16*  WgcT0  = (bf16*)alloc(256 * 64 * 2);
    bf16*  WgcT1  = (bf16*)alloc(256 * 64 * 2);
    float* bgc0   = (float*)alloc(256 * 4);
    float* bgc1   = (float*)alloc(256 * 4);
    float* ct0    = (float*)alloc((size_t)N_ * B_ * 64 * 4);
    float* ct1    = (float*)alloc((size_t)N_ * B_ * 64 * 4);
    float* hl0    = (float*)alloc((size_t)N_ * B_ * 64 * 4);
    float* hl1    = (float*)alloc((size_t)N_ * B_ * 64 * 4);
    size_t fixed = off;

    // per-LC-unit scratch: VcatT 6MiB + HG 2MiB + ht0c 2MiB = 10MiB
    static const int divs[] = {16, 12, 8, 6, 4, 2, 1};
    int LC = 1;
    for (int di = 0; di < 7; ++di) {
        if (fixed + (size_t)divs[di] * 10485760ull + 65536 <= ws_size) { LC = divs[di]; break; }
    }
    bf16*  VcatT = (bf16*)alloc((size_t)LC * 6291456ull);   // (LC*1024) x 3072
    bf16*  HG    = (bf16*)alloc((size_t)LC * 2097152ull);   // 1024 x (LC*1024)
    bf16*  ht0c  = (bf16*)alloc((size_t)LC * 2097152ull);   // Mrows x 64

    dim3 blk(256);
    bf16*  McatB[2] = {Mcatb0, Mcatb1};
    bf16*  WgcT[2] = {WgcT0, WgcT1};
    float* bgc[2] = {bgc0, bgc1};

    f2b_kernel<<<4096, blk, 0, stream>>>(adj, adjb, 1024 * 1024);
    for (int z = 0; z < 2; ++z) {
        const float* Ez = E + (size_t)z * N_ * 64;
        gemm_nn<<<dim3(1, 16), blk, 0, stream>>>(Ez, Wq + z * 4096, qb, 1024, 64, 64, 64, 64, 64, nullptr);
        gemm_nn<<<dim3(1, 16), blk, 0, stream>>>(Ez, Wk + z * 4096, kb, 1024, 64, 64, 64, 64, 64, nullptr);
        gemm_nt<<<dim3(16, 16), blk, 0, stream>>>(qb, kb, logits, 1024, 64, 0.125f);
        row_softmax<<<1024, blk, 0, stream>>>(logits, attnf, 1024, McatB[z] + 2048, 3072, 0);
        transpose_f2b<<<dim3(16, 16), blk, 0, stream>>>(attnf, attnT);
        gemm_nt<<<dim3(16, 16), blk, 0, stream>>>(Eg1 + z * 16384, Eg2 + z * 16384, logits, 1024, 16, 1.f);
        row_softmax<<<1024, blk, 0, stream>>>(logits, nullptr, 0, adpb, 1024, 1);
        gemm_mfma<1, 0><<<dim3(8, 8), blk, 0, stream>>>(adjb, attnT, McatB[z],
            1024, 1024, 1024, 1024, 1024, 3072, nullptr, 1024);
        gemm_mfma<1, 0><<<dim3(8, 8), blk, 0, stream>>>(adpb, attnT, McatB[z] + 1024,
            1024, 1024, 1024, 1024, 1024, 3072, nullptr, 1024);
        if (z == 0) {
            for (int kp = 0; kp < 3; ++kp)
                gemm_nn<<<dim3(1, 1), blk, 0, stream>>>(Wv0, Wmix + kp * 4096,
                    Wvc0 + kp * 3 * 64, 3, 64, 64, 64, 64, 64, nullptr);
        } else {
            for (int kp = 0; kp < 3; ++kp)
                gemm_nn<<<dim3(1, 1), blk, 0, stream>>>(Wv1, Wmix + 12288 + kp * 4096,
                    Wvc1 + kp * 4096, 64, 64, 64, 64, 64, 64, nullptr);
            wvc1t_kernel<<<64, blk, 0, stream>>>(Wvc1, Wvc1T);
        }
        wgct_kernel<<<64, blk, 0, stream>>>(Wg + z * 16384, WgcT[z]);
        bias_kernel<<<1, blk, 0, stream>>>(bv + z * 64, Wmix + z * 12288, bmix + z * 64,
            Wg + z * 16384, bg + z * 256, bgc[z]);
    }

    const int nch = L_ / LC;
    dim3 blk512(512);
    for (int c = 0; c < nch; ++c) {
        const int l0 = c * LC;
        // ---- layer 0 ----
        vcat0T_kernel<<<dim3(LC * 16, 4), blk, 0, stream>>>(hist, Wvc0, VcatT, l0, LC);
        gemm_pipe<<<dim3(LC * 4, 4), blk512, 0, stream>>>(Mcatb0, VcatT, HG,
            LC * 1024, 3072);
        fused_gates_scan<<<1024, blk, 0, stream>>>(HG, WgcT0, bgc0, ct0,
            ht0c, hl0, LC, l0, c == 0);
        // ---- layer 1: V build straight into VcatT (REMAP epilogue) ----
        gemm_mfma<1, 1><<<dim3(8, 2, LC * 16), blk, 0, stream>>>(Wvc1T, ht0c, VcatT,
            256, 1024, 64, 64, LC * 1024, 0, nullptr, 192);
        gemm_pipe<<<dim3(LC * 4, 4), blk512, 0, stream>>>(Mcatb1, VcatT, HG,
            LC * 1024, 3072);
        fused_gates_scan<<<1024, blk, 0, stream>>>(HG, WgcT1, bgc1, ct1,
            nullptr, hl1, LC, l0, c == 0);
    }
    decoder_kernel<<<64, blk, 0, stream>>>(hl0, hl1, Wdec, bdec, Wout, bout, outp);
}

// Round 7
// 2115.499 us; speedup vs baseline: 1.2951x; 1.0269x over previous
//
#include <hip/hip_runtime.h>
#include <hip/hip_bf16.h>

#define B_ 16
#define L_ 96
#define N_ 1024
#define EMB_ 64

typedef __hip_bfloat16 bf16;
typedef __attribute__((ext_vector_type(4))) float f32x4;
typedef __attribute__((ext_vector_type(8))) short s16x8;

// ================= fp32 GEMM (NN), small setup mats only =================
__global__ __launch_bounds__(256) void gemm_nn(
    const float* __restrict__ A, const float* __restrict__ Bm, float* __restrict__ C,
    int M, int N, int K, int lda, int ldb, int ldc, const float* __restrict__ bias)
{
    __shared__ float As[64][17];
    __shared__ __align__(16) float Bs[16][64];
    const int tid = threadIdx.x;
    const int tx = tid & 15, ty = tid >> 4;
    const int row0 = blockIdx.y * 64, col0 = blockIdx.x * 64;
    float acc[4][4] = {};
    const int ak = tid & 15, ar = tid >> 4;
    const int bc = tid & 63, bk = tid >> 6;
    for (int k0 = 0; k0 < K; k0 += 16) {
#pragma unroll
        for (int i = 0; i < 4; ++i) {
            int r = ar + i * 16;
            int gr = row0 + r, gk = k0 + ak;
            As[r][ak] = (gr < M && gk < K) ? A[(size_t)gr * lda + gk] : 0.f;
        }
#pragma unroll
        for (int i = 0; i < 4; ++i) {
            int kk = bk + i * 4;
            int gk = k0 + kk, gc = col0 + bc;
            Bs[kk][bc] = (gk < K && gc < N) ? Bm[(size_t)gk * ldb + gc] : 0.f;
        }
        __syncthreads();
#pragma unroll
        for (int kk = 0; kk < 16; ++kk) {
            float4 b4 = *reinterpret_cast<const float4*>(&Bs[kk][tx * 4]);
            float a0 = As[ty * 4 + 0][kk];
            float a1 = As[ty * 4 + 1][kk];
            float a2 = As[ty * 4 + 2][kk];
            float a3 = As[ty * 4 + 3][kk];
            acc[0][0] += a0 * b4.x; acc[0][1] += a0 * b4.y; acc[0][2] += a0 * b4.z; acc[0][3] += a0 * b4.w;
            acc[1][0] += a1 * b4.x; acc[1][1] += a1 * b4.y; acc[1][2] += a1 * b4.z; acc[1][3] += a1 * b4.w;
            acc[2][0] += a2 * b4.x; acc[2][1] += a2 * b4.y; acc[2][2] += a2 * b4.z; acc[2][3] += a2 * b4.w;
            acc[3][0] += a3 * b4.x; acc[3][1] += a3 * b4.y; acc[3][2] += a3 * b4.z; acc[3][3] += a3 * b4.w;
        }
        __syncthreads();
    }
#pragma unroll
    for (int i = 0; i < 4; ++i) {
        int gr = row0 + ty * 4 + i;
        if (gr >= M) continue;
#pragma unroll
        for (int j = 0; j < 4; ++j) {
            int gc = col0 + tx * 4 + j;
            if (gc >= N) continue;
            float v = acc[i][j];
            if (bias) v += bias[gc];
            C[(size_t)gr * ldc + gc] = v;
        }
    }
}

// ================= fp32 GEMM (NT) small, for setup =================
__global__ __launch_bounds__(256) void gemm_nt(
    const float* __restrict__ A, const float* __restrict__ Bm, float* __restrict__ C,
    int N, int K, float alpha)
{
    __shared__ float As[64][65];
    __shared__ float Bs[64][65];
    const int tid = threadIdx.x;
    const int row0 = blockIdx.y * 64, col0 = blockIdx.x * 64;
    for (int idx = tid; idx < 64 * K; idx += 256) {
        int r = idx / K, c = idx % K;
        As[r][c] = A[(size_t)(row0 + r) * K + c];
        Bs[r][c] = Bm[(size_t)(col0 + r) * K + c];
    }
    __syncthreads();
    const int tx = tid & 15, ty = tid >> 4;
    float acc[4][4] = {};
    for (int c = 0; c < K; ++c) {
        float a[4], b[4];
#pragma unroll
        for (int i = 0; i < 4; ++i) a[i] = As[ty * 4 + i][c];
#pragma unroll
        for (int j = 0; j < 4; ++j) b[j] = Bs[tx * 4 + j][c];
#pragma unroll
        for (int i = 0; i < 4; ++i)
#pragma unroll
            for (int j = 0; j < 4; ++j) acc[i][j] += a[i] * b[j];
    }
#pragma unroll
    for (int i = 0; i < 4; ++i)
#pragma unroll
        for (int j = 0; j < 4; ++j)
            C[(size_t)(row0 + ty * 4 + i) * N + col0 + tx * 4 + j] = alpha * acc[i][j];
}

// ======= row softmax over 1024 cols; optional fp32 and/or bf16 outputs =======
__global__ __launch_bounds__(256) void row_softmax(
    const float* __restrict__ in, float* __restrict__ out32, int os32,
    bf16* __restrict__ out16, int os16, int relu)
{
    const float* rp = in + (size_t)blockIdx.x * N_;
    const int tid = threadIdx.x;
    float v[4];
#pragma unroll
    for (int j = 0; j < 4; ++j) {
        float x = rp[tid + 256 * j];
        if (relu) x = fmaxf(x, 0.f);
        v[j] = x;
    }
    float m = fmaxf(fmaxf(v[0], v[1]), fmaxf(v[2], v[3]));
#pragma unroll
    for (int off = 32; off > 0; off >>= 1) m = fmaxf(m, __shfl_xor(m, off));
    __shared__ float red[4], red2[4];
    int w = tid >> 6;
    if ((tid & 63) == 0) red[w] = m;
    __syncthreads();
    m = fmaxf(fmaxf(red[0], red[1]), fmaxf(red[2], red[3]));
    float s = 0.f;
#pragma unroll
    for (int j = 0; j < 4; ++j) { v[j] = __expf(v[j] - m); s += v[j]; }
#pragma unroll
    for (int off = 32; off > 0; off >>= 1) s += __shfl_xor(s, off);
    if ((tid & 63) == 0) red2[w] = s;
    __syncthreads();
    s = red2[0] + red2[1] + red2[2] + red2[3];
    float inv = 1.f / s;
#pragma unroll
    for (int j = 0; j < 4; ++j) {
        float r = v[j] * inv;
        if (out32) out32[(size_t)blockIdx.x * os32 + tid + 256 * j] = r;
        if (out16) out16[(size_t)blockIdx.x * os16 + tid + 256 * j] = __float2bfloat16(r);
    }
}

// ======= transpose 1024x1024 fp32 -> bf16 (out[r][c] = in[c][r]) =======
__global__ __launch_bounds__(256) void transpose_f2b(
    const float* __restrict__ in, bf16* __restrict__ out)
{
    __shared__ float t[64][65];
    const int cx = blockIdx.x, cy = blockIdx.y;
    const int tid = threadIdx.x;
#pragma unroll
    for (int k = 0; k < 16; ++k) {
        int idx = k * 256 + tid;
        int r = idx >> 6, c = idx & 63;
        t[r][c] = in[(size_t)(cy * 64 + r) * 1024 + cx * 64 + c];
    }
    __syncthreads();
#pragma unroll
    for (int k = 0; k < 16; ++k) {
        int idx = k * 256 + tid;
        int r = idx >> 6, c = idx & 63;
        out[(size_t)(cx * 64 + r) * 1024 + cy * 64 + c] = __float2bfloat16(t[c][r]);
    }
}

// ================= WgcT[(g*64+f)][e] = Wg[g][e][f], bf16 =================
__global__ __launch_bounds__(256) void wgct_kernel(const float* __restrict__ Wg,
                                                   bf16* __restrict__ WgcT)
{
    int i = blockIdx.x * 256 + threadIdx.x;  // 16384
    int g = i >> 12, e = (i >> 6) & 63, f = i & 63;
    WgcT[(((size_t)g * 64 + f) << 6) + e] = __float2bfloat16(Wg[i]);
}

// ====== Wvc1T[(kp*64+e)][f] = Wvc1[kp][f][e], bf16, padded to 256 rows ======
__global__ __launch_bounds__(256) void wvc1t_kernel(const float* __restrict__ Wvc1,
                                                    bf16* __restrict__ WT)
{
    int i = blockIdx.x * 256 + threadIdx.x;  // 256*64
    int row = i >> 6, f = i & 63;
    float v = 0.f;
    if (row < 192) { int kp = row >> 6, e = row & 63; v = Wvc1[kp * 4096 + f * 64 + e]; }
    WT[i] = __float2bfloat16(v);
}

// ================= fp32 -> bf16 convert =================
__global__ __launch_bounds__(256) void f2b_kernel(const float* __restrict__ in,
                                                  bf16* __restrict__ out, int n)
{
    int i = blockIdx.x * 256 + threadIdx.x;
    if (i < n) out[i] = __float2bfloat16(in[i]);
}

// ================= folded gate bias =================
__global__ __launch_bounds__(256) void bias_kernel(
    const float* __restrict__ bvz, const float* __restrict__ Wmz, const float* __restrict__ bmz,
    const float* __restrict__ Wgz, const float* __restrict__ bgz, float* __restrict__ bgconst)
{
    __shared__ float bconst[64];
    const int tid = threadIdx.x;
    if (tid < 64) {
        float s = bmz[tid];
        for (int kp = 0; kp < 3; ++kp)
            for (int f = 0; f < 64; ++f) s += bvz[f] * Wmz[kp * 4096 + f * 64 + tid];
        bconst[tid] = s;
    }
    __syncthreads();
    int g = tid >> 6, fo = tid & 63;
    float s = bgz[g * 64 + fo];
    for (int e = 0; e < 64; ++e) s += bconst[e] * Wgz[g * 4096 + e * 64 + fo];
    bgconst[tid] = s;
}

// ====== VcatT build for layer 0: VcatT[(l*16+b)*64+e][kp*1024+n], bf16 ======
__global__ __launch_bounds__(256) void vcat0T_kernel(
    const float* __restrict__ hist, const float* __restrict__ Wvc0,
    bf16* __restrict__ VcatT, int l0, int LC)
{
    __shared__ float xs[3][1024];
    __shared__ float Ws[576];
    const int lb = blockIdx.x;   // l*16+b
    const int l = lb >> 4, b = lb & 15;
    const int eq = blockIdx.y;   // e quarter
    const int tid = threadIdx.x;
    for (int i = tid; i < 576; i += 256) Ws[i] = Wvc0[i];
    const float* xp = hist + ((size_t)b * L_ + (l0 + l)) * N_ * 3;
    for (int i = tid; i < 3072; i += 256) xs[i % 3][i / 3] = xp[i];
    __syncthreads();
    bf16* outb = VcatT + (size_t)lb * 64 * 3072;
#pragma unroll
    for (int kp = 0; kp < 3; ++kp)
        for (int ei = 0; ei < 16; ++ei) {
            int e = eq * 16 + ei;
            float w0 = Ws[kp * 192 + e], w1 = Ws[kp * 192 + 64 + e], w2 = Ws[kp * 192 + 128 + e];
            bf16* rp = outb + (size_t)e * 3072 + kp * 1024;
#pragma unroll
            for (int q = 0; q < 4; ++q) {
                int n = q * 256 + tid;
                rp[n] = __float2bfloat16(fmaf(xs[0][n], w0, fmaf(xs[1][n], w1, xs[2][n] * w2)));
            }
        }
}

__device__ __forceinline__ void gload16(const bf16* g, bf16* l)
{
    __builtin_amdgcn_global_load_lds((const __attribute__((address_space(1))) void*)g,
                                     (__attribute__((address_space(3))) void*)l, 16, 0, 0);
}

// ================= bf16 MFMA GEMM (NT): C = A @ BT^T, 128^2 tile (K=64..1024) =================
template <int OUT_BF16, int REMAP>
__global__ __launch_bounds__(256) void gemm_mfma(
    const bf16* __restrict__ A, const bf16* __restrict__ BT, void* __restrict__ Cp,
    int M, int N, int K, int lda, int ldb, int ldc,
    const float* __restrict__ bias, int Nmask)
{
    __shared__ __align__(16) bf16 As[128 * 64];
    __shared__ __align__(16) bf16 Bs[128 * 64];
    const int tid = threadIdx.x;
    const int lane = tid & 63, w = tid >> 6;
    const int wr = w >> 1, wc = w & 1;
    const int row0 = blockIdx.y * 128, col0 = blockIdx.x * 128;
    if (REMAP) BT += (size_t)blockIdx.z * 64;

    f32x4 acc[4][4];
#pragma unroll
    for (int i = 0; i < 4; ++i)
#pragma unroll
        for (int j = 0; j < 4; ++j) acc[i][j] = (f32x4){0.f, 0.f, 0.f, 0.f};

    const int srow = w * 32 + (lane >> 3);
    const int scolsw = ((lane & 7) ^ (lane >> 3)) * 8;   // pre-swizzled k offset

    for (int k0 = 0; k0 < K; k0 += 64) {
#pragma unroll
        for (int i = 0; i < 4; ++i) {
            gload16(A + (size_t)(row0 + srow + i * 8) * lda + k0 + scolsw,
                    &As[(w * 32 + i * 8) * 64]);
            gload16(BT + (size_t)(col0 + srow + i * 8) * ldb + k0 + scolsw,
                    &Bs[(w * 32 + i * 8) * 64]);
        }
        __syncthreads();
#pragma unroll
        for (int kk = 0; kk < 64; kk += 32) {
            s16x8 af[4], bfr[4];
            const int ko = (kk + (lane >> 4) * 8) ^ ((lane & 7) << 3);
#pragma unroll
            for (int mi = 0; mi < 4; ++mi)
                af[mi] = *(const s16x8*)&As[(wr * 64 + mi * 16 + (lane & 15)) * 64 + ko];
#pragma unroll
            for (int ni = 0; ni < 4; ++ni)
                bfr[ni] = *(const s16x8*)&Bs[(wc * 64 + ni * 16 + (lane & 15)) * 64 + ko];
#pragma unroll
            for (int mi = 0; mi < 4; ++mi)
#pragma unroll
                for (int ni = 0; ni < 4; ++ni)
                    acc[mi][ni] = __builtin_amdgcn_mfma_f32_16x16x32_bf16(
                        af[mi], bfr[ni], acc[mi][ni], 0, 0, 0);
        }
        __syncthreads();
    }

    if (REMAP) {
        bf16* outb = (bf16*)Cp + (size_t)blockIdx.z * (64 * 3072);
#pragma unroll
        for (int mi = 0; mi < 4; ++mi) {
            const int gr = row0 + wr * 64 + mi * 16 + (lane >> 4) * 4;
#pragma unroll
            for (int ni = 0; ni < 4; ++ni) {
                const int gc = col0 + wc * 64 + ni * 16 + (lane & 15);
#pragma unroll
                for (int j = 0; j < 4; ++j) {
                    const int r = gr + j;
                    if (r >= Nmask) continue;
                    outb[(size_t)(r & 63) * 3072 + (r >> 6) * 1024 + gc] =
                        __float2bfloat16(acc[mi][ni][j]);
                }
            }
        }
        return;
    }

#pragma unroll
    for (int mi = 0; mi < 4; ++mi) {
        const int gr = row0 + wr * 64 + mi * 16 + (lane >> 4) * 4;
#pragma unroll
        for (int ni = 0; ni < 4; ++ni) {
            const int gc = col0 + wc * 64 + ni * 16 + (lane & 15);
            if (gc >= Nmask) continue;
            const float bb = bias ? bias[gc] : 0.f;
#pragma unroll
            for (int j = 0; j < 4; ++j) {
                float v = acc[mi][ni][j] + bb;
                if (OUT_BF16)
                    ((bf16*)Cp)[(size_t)(gr + j) * ldc + gc] = __float2bfloat16(v);
                else
                    ((float*)Cp)[(size_t)(gr + j) * ldc + gc] = v;
            }
        }
    }
}

// ====== 8-phase pipelined bf16 MFMA GEMM (NT), 256x256 tile, BK=64 ======
// C = A @ BT^T. lda = ldb = K, ldc = N. M%256==0, N%256==0, K%128==0.
// 512 thr = 8 waves (2M x 4N), per-wave 128x64. LDS: 2 dbuf x {A,B} x 2 halves
// x (128 rows x 64) = 128 KiB. Per iteration: 2 K-tiles, 8 phases; each phase
// stages exactly ONE half-tile; counted vmcnt(2) before ph1/ph5 (never 0 except
// the final tile). Swizzle: 16B slot ^= (row&7), inverse on global source.
__global__ __launch_bounds__(512) void gemm_pipe(
    const bf16* __restrict__ A, const bf16* __restrict__ BT, bf16* __restrict__ C,
    int N, int K)
{
    __shared__ __align__(16) bf16 lds[8 * 8192];   // [d][mat][half] 16KB half-tiles
    const int tid = threadIdx.x;
    const int lane = tid & 63, w = tid >> 6;
    const int wm = w >> 2, wn = w & 3, bh = wn >> 1;
    const int row0 = blockIdx.y * 256, col0 = blockIdx.x * 256;

    const int strow = tid >> 3;                              // 0..63
    const int srck  = ((tid & 7) ^ ((tid >> 3) & 7)) << 3;   // inverse swizzle (elems)
    const int e7 = lane & 7, fs = lane >> 4, a15 = lane & 15;

    int aoff0[8], boff0[4];
#pragma unroll
    for (int mi = 0; mi < 8; ++mi)
        aoff0[mi] = (mi * 16 + a15) * 64 + ((fs ^ e7) << 3);
#pragma unroll
    for (int ni = 0; ni < 4; ++ni)
        boff0[ni] = ((wn & 1) * 64 + ni * 16 + a15) * 64 + ((fs ^ e7) << 3);

    auto stage = [&](int mat, int half, int kt) {
        bf16* dst = &lds[(size_t)((((kt & 1) << 1) | mat) * 2 + half) * 8192 + w * 512];
        const bf16* src = (mat ? BT + (size_t)col0 * K : A + (size_t)row0 * K)
                          + (size_t)(half * 128) * K + kt * 64 + srck;
        gload16(src + (size_t)strow * K, dst);
        gload16(src + (size_t)(64 + strow) * K, dst + 4096);
    };

    f32x4 acc[8][4];
#pragma unroll
    for (int i = 0; i < 8; ++i)
#pragma unroll
        for (int j = 0; j < 4; ++j) acc[i][j] = (f32x4){0.f, 0.f, 0.f, 0.f};

    s16x8 b0, b1, b2, b3;

#define MF_(a, mi) { \
    acc[mi][0] = __builtin_amdgcn_mfma_f32_16x16x32_bf16(a, b0, acc[mi][0], 0, 0, 0); \
    acc[mi][1] = __builtin_amdgcn_mfma_f32_16x16x32_bf16(a, b1, acc[mi][1], 0, 0, 0); \
    acc[mi][2] = __builtin_amdgcn_mfma_f32_16x16x32_bf16(a, b2, acc[mi][2], 0, 0, 0); \
    acc[mi][3] = __builtin_amdgcn_mfma_f32_16x16x32_bf16(a, b3, acc[mi][3], 0, 0, 0); }

#define PH_(d, kh, g, DOB, STG) { \
    const bf16* Ab = &lds[((d) * 4 + wm) * 8192]; \
    const bf16* Bb = &lds[((d) * 4 + 2 + bh) * 8192]; \
    if (DOB) { \
        b0 = *(const s16x8*)&Bb[boff0[0] ^ ((kh) * 32)]; \
        b1 = *(const s16x8*)&Bb[boff0[1] ^ ((kh) * 32)]; \
        b2 = *(const s16x8*)&Bb[boff0[2] ^ ((kh) * 32)]; \
        b3 = *(const s16x8*)&Bb[boff0[3] ^ ((kh) * 32)]; \
    } \
    s16x8 a0 = *(const s16x8*)&Ab[aoff0[(g) * 4 + 0] ^ ((kh) * 32)]; \
    s16x8 a1 = *(const s16x8*)&Ab[aoff0[(g) * 4 + 1] ^ ((kh) * 32)]; \
    s16x8 a2 = *(const s16x8*)&Ab[aoff0[(g) * 4 + 2] ^ ((kh) * 32)]; \
    s16x8 a3 = *(const s16x8*)&Ab[aoff0[(g) * 4 + 3] ^ ((kh) * 32)]; \
    STG; \
    __builtin_amdgcn_s_barrier(); \
    asm volatile("s_waitcnt lgkmcnt(0)" ::: "memory"); \
    __builtin_amdgcn_sched_barrier(0); \
    __builtin_amdgcn_s_setprio(1); \
    MF_(a0, (g) * 4 + 0); MF_(a1, (g) * 4 + 1); \
    MF_(a2, (g) * 4 + 2); MF_(a3, (g) * 4 + 3); \
    __builtin_amdgcn_s_setprio(0); \
    __builtin_amdgcn_s_barrier(); }

    const int NT = K >> 6;   // even
    // prologue: tile0 fully -> buf0; A-lo of tile1 -> buf1   (10 loads/thread)
    stage(0, 0, 0); stage(0, 1, 0); stage(1, 0, 0); stage(1, 1, 0);
    stage(0, 0, 1);

    for (int i = 0; i < NT / 2; ++i) {
        const int kt = 2 * i;
        // tile kt landed (allow 2 newest: A-lo(kt+1))
        asm volatile("s_waitcnt vmcnt(2)" ::: "memory");
        __builtin_amdgcn_sched_barrier(0);
        __builtin_amdgcn_s_barrier();
        PH_(0, 0, 0, 1, { stage(0, 1, kt + 1); });                    // ph1: A-hi(kt+1)
        PH_(0, 0, 1, 0, { stage(1, 0, kt + 1); });                    // ph2: B-lo(kt+1)
        PH_(0, 1, 0, 1, { stage(1, 1, kt + 1); });                    // ph3: B-hi(kt+1)
        PH_(0, 1, 1, 0, { if (kt + 2 < NT) stage(0, 0, kt + 2); });   // ph4: A-lo(kt+2)
        // tile kt+1 landed (allow 2 newest: A-lo(kt+2) if staged)
        if (kt + 2 < NT) { asm volatile("s_waitcnt vmcnt(2)" ::: "memory"); }
        else             { asm volatile("s_waitcnt vmcnt(0)" ::: "memory"); }
        __builtin_amdgcn_sched_barrier(0);
        __builtin_amdgcn_s_barrier();
        PH_(1, 0, 0, 1, { if (kt + 2 < NT) stage(0, 1, kt + 2); });   // ph5: A-hi(kt+2)
        PH_(1, 0, 1, 0, { if (kt + 2 < NT) stage(1, 0, kt + 2); });   // ph6: B-lo(kt+2)
        PH_(1, 1, 0, 1, { if (kt + 2 < NT) stage(1, 1, kt + 2); });   // ph7: B-hi(kt+2)
        PH_(1, 1, 1, 0, { if (kt + 3 < NT) stage(0, 0, kt + 3); });   // ph8: A-lo(kt+3)
    }
#undef PH_
#undef MF_

#pragma unroll
    for (int mi = 0; mi < 8; ++mi) {
        const int gr = row0 + wm * 128 + mi * 16 + (lane >> 4) * 4;
#pragma unroll
        for (int ni = 0; ni < 4; ++ni) {
            const int gc = col0 + wn * 64 + ni * 16 + (lane & 15);
#pragma unroll
            for (int j = 0; j < 4; ++j)
                C[(size_t)(gr + j) * N + gc] = __float2bfloat16(acc[mi][ni][j]);
        }
    }
}

// ========== fused gates GEMM + IN-REGISTER LSTM scan ==========
__global__ __launch_bounds__(256, 4) void fused_gates_scan(
    const bf16* __restrict__ HG, const bf16* __restrict__ WgcT,
    const float* __restrict__ bgc, float* __restrict__ ct_buf,
    bf16* __restrict__ ht_out, float* __restrict__ htlast,
    int LC, int l0, int initct)
{
    __shared__ __align__(16) bf16 Bs[256 * 64];
    __shared__ float bgs[256];
    const int tid = threadIdx.x;
    const int lane = tid & 63, w = tid >> 6;
    const int n = blockIdx.x;
    const int swz = ((lane & 7) ^ (lane >> 3)) * 8;
    const int l8 = (lane >> 3) * 64;

#pragma unroll
    for (int r = 0; r < 8; ++r)
        gload16(WgcT + r * 2048 + w * 512 + l8 + swz, &Bs[r * 2048 + w * 512]);
    bgs[tid] = bgc[tid];
    __syncthreads();

    const int ar = lane & 15;
    const int ak = (lane >> 4) * 8;
    const int kswz = (lane & 7) << 3;
    const int f = w * 16 + ar;
    const int r0 = (lane >> 4) * 4;
    const float bgf = bgs[f], bgi = bgs[64 + f], bgg = bgs[128 + f], bgo = bgs[192 + f];

    float ct[4];
    const size_t cbase = (size_t)n * 1024;
#pragma unroll
    for (int j = 0; j < 4; ++j)
        ct[j] = initct ? 0.f : ct_buf[cbase + (size_t)(r0 + j) * 64 + f];

    const bf16* HGn = HG + (size_t)n * LC * 1024;
    s16x8 a0 = *(const s16x8*)&HGn[ar * 64 + ak];
    s16x8 a1 = *(const s16x8*)&HGn[ar * 64 + ak + 32];

    for (int l = 0; l < LC; ++l) {
        s16x8 p0 = a0, p1 = a1;
        if (l + 1 < LC) {
            p0 = *(const s16x8*)&HGn[((l + 1) * 16 + ar) * 64 + ak];
            p1 = *(const s16x8*)&HGn[((l + 1) * 16 + ar) * 64 + ak + 32];
        }
        f32x4 acc[4];
#pragma unroll
        for (int ni = 0; ni < 4; ++ni) acc[ni] = (f32x4){0.f, 0.f, 0.f, 0.f};
#pragma unroll
        for (int ni = 0; ni < 4; ++ni) {
            s16x8 bf = *(const s16x8*)&Bs[(ni * 64 + w * 16 + ar) * 64 + (ak ^ kswz)];
            acc[ni] = __builtin_amdgcn_mfma_f32_16x16x32_bf16(a0, bf, acc[ni], 0, 0, 0);
        }
#pragma unroll
        for (int ni = 0; ni < 4; ++ni) {
            s16x8 bf = *(const s16x8*)&Bs[(ni * 64 + w * 16 + ar) * 64 + ((ak + 32) ^ kswz)];
            acc[ni] = __builtin_amdgcn_mfma_f32_16x16x32_bf16(a1, bf, acc[ni], 0, 0, 0);
        }
        const size_t hbase = ((size_t)n * LC + l) * 1024;
        const bool last = (l0 + l == L_ - 1);
#pragma unroll
        for (int j = 0; j < 4; ++j) {
            float xf = acc[0][j] + bgf;
            float xi = acc[1][j] + bgi;
            float xg = acc[2][j] + bgg;
            float xo = acc[3][j] + bgo;
            float fg = 1.f / (1.f + __expf(-xf));
            float ig = 1.f / (1.f + __expf(-xi));
            float gg = 2.f / (1.f + __expf(-2.f * xg)) - 1.f;
            float og = 1.f / (1.f + __expf(-xo));
            ct[j] = fg * ct[j] + ig * gg;
            float ht = og * (2.f / (1.f + __expf(-2.f * ct[j])) - 1.f);
            if (ht_out) ht_out[hbase + (size_t)(r0 + j) * 64 + f] = __float2bfloat16(ht);
            if (htlast && last) htlast[cbase + (size_t)(r0 + j) * 64 + f] = ht;
        }
        a0 = p0; a1 = p1;
    }
#pragma unroll
    for (int j = 0; j < 4; ++j)
        ct_buf[cbase + (size_t)(r0 + j) * 64 + f] = ct[j];
}

// ================= decoder =================
__global__ __launch_bounds__(256) void decoder_kernel(
    const float* __restrict__ h0, const float* __restrict__ h1,
    const float* __restrict__ Wdec, const float* __restrict__ bdec,
    const float* __restrict__ Wout, const float* __restrict__ bout,
    float* __restrict__ outp)
{
    __shared__ float Wd[12 * 2 * 64];
    __shared__ float Wo[144];
    __shared__ float bd[12], bo[12];
    const int tid = threadIdx.x;
    for (int i = tid; i < 12 * 2 * 64; i += 256) Wd[i] = Wdec[i];
    for (int i = tid; i < 144; i += 256) Wo[i] = Wout[i];
    if (tid < 12) { bd[tid] = bdec[tid]; bo[tid] = bout[tid]; }
    __syncthreads();
    const int gid = blockIdx.x * 256 + tid;   // b*1024 + n
    const int b = gid >> 10, n = gid & 1023;
    const float* h0r = h0 + ((size_t)n * 16 + b) * 64;
    const float* h1r = h1 + ((size_t)n * 16 + b) * 64;
    float dec[12];
#pragma unroll
    for (int o = 0; o < 12; ++o) dec[o] = bd[o];
    for (int e = 0; e < 64; ++e) {
        float v0 = h0r[e], v1 = h1r[e];
#pragma unroll
        for (int o = 0; o < 12; ++o) dec[o] += v0 * Wd[o * 128 + e] + v1 * Wd[o * 128 + 64 + e];
    }
#pragma unroll
    for (int o = 0; o < 12; ++o) {
        float s = bo[o];
#pragma unroll
        for (int p = 0; p < 12; ++p) s += Wo[o * 12 + p] * dec[p];
        outp[((size_t)b * 12 + o) * 1024 + n] = s;
    }
}

extern "C" void kernel_launch(void* const* d_in, const int* in_sizes, int n_in,
                              void* d_out, int out_size, void* d_ws, size_t ws_size,
                              hipStream_t stream)
{
    const float* hist = (const float*)d_in[0];
    const float* adj  = (const float*)d_in[1];
    const float* Wv0  = (const float*)d_in[2];
    const float* Wv1  = (const float*)d_in[3];
    const float* bv   = (const float*)d_in[4];
    const float* E    = (const float*)d_in[5];
    const float* Wq   = (const float*)d_in[6];
    const float* Wk   = (const float*)d_in[7];
    const float* Eg1  = (const float*)d_in[8];
    const float* Eg2  = (const float*)d_in[9];
    const float* Wmix = (const float*)d_in[10];
    const float* bmix = (const float*)d_in[11];
    const float* Wg   = (const float*)d_in[12];
    const float* bg   = (const float*)d_in[13];
    const float* Wdec = (const float*)d_in[14];
    const float* bdec = (const float*)d_in[15];
    const float* Wout = (const float*)d_in[16];
    const float* bout = (const float*)d_in[17];
    float* outp = (float*)d_out;
    (void)in_sizes; (void)n_in; (void)out_size;

    char* ws = (char*)d_ws;
    size_t off = 0;
    auto alloc = [&](size_t bytes) -> void* {
        void* p = (void*)(ws + off);
        off += (bytes + 255) & ~(size_t)255;
        return p;
    };
    bf16*  Mcatb0 = (bf16*)alloc((size_t)1024 * 3072 * 2);   // [M1|M2|attn] bf16
    bf16*  Mcatb1 = (bf16*)alloc((size_t)1024 * 3072 * 2);
    float* attnf  = (float*)alloc((size_t)1024 * 1024 * 4);
    bf16*  attnT  = (bf16*)alloc((size_t)1024 * 1024 * 2);
    bf16*  adjb   = (bf16*)alloc((size_t)1024 * 1024 * 2);
    bf16*  adpb   = (bf16*)alloc((size_t)1024 * 1024 * 2);
    float* qb     = (float*)alloc((size_t)1024 * 64 * 4);
    float* kb     = (float*)alloc((size_t)1024 * 64 * 4);
    float* logits = (float*)alloc((size_t)1024 * 1024 * 4);
    float* Wvc0   = (float*)alloc(3 * 3 * 64 * 4);           // [kp][c][e]
    float* Wvc1   = (float*)alloc(3 * 64 * 64 * 4);          // [kp][f][e]
    bf16*  Wvc1T  = (bf16*)alloc(256 * 64 * 2);
    bf16*  WgcT0  = (bf16*)alloc(256 * 64 * 2);
    bf16*  WgcT1  = (bf16*)alloc(256 * 64 * 2);
    float* bgc0   = (float*)alloc(256 * 4);
    float* bgc1   = (float*)alloc(256 * 4);
    float* ct0    = (float*)alloc((size_t)N_ * B_ * 64 * 4);
    float* ct1    = (float*)alloc((size_t)N_ * B_ * 64 * 4);
    float* hl0    = (float*)alloc((size_t)N_ * B_ * 64 * 4);
    float* hl1    = (float*)alloc((size_t)N_ * B_ * 64 * 4);
    size_t fixed = off;

    // per-LC-unit scratch: VcatT 6MiB + HG 2MiB + ht0c 2MiB = 10MiB
    static const int divs[] = {16, 12, 8, 6, 4, 2, 1};
    int LC = 1;
    for (int di = 0; di < 7; ++di) {
        if (fixed + (size_t)divs[di] * 10485760ull + 65536 <= ws_size) { LC = divs[di]; break; }
    }
    bf16*  VcatT = (bf16*)alloc((size_t)LC * 6291456ull);   // (LC*1024) x 3072
    bf16*  HG    = (bf16*)alloc((size_t)LC * 2097152ull);   // 1024 x (LC*1024)
    bf16*  ht0c  = (bf16*)alloc((size_t)LC * 2097152ull);   // Mrows x 64

    dim3 blk(256);
    bf16*  McatB[2] = {Mcatb0, Mcatb1};
    bf16*  WgcT[2] = {WgcT0, WgcT1};
    float* bgc[2] = {bgc0, bgc1};

    f2b_kernel<<<4096, blk, 0, stream>>>(adj, adjb, 1024 * 1024);
    for (int z = 0; z < 2; ++z) {
        const float* Ez = E + (size_t)z * N_ * 64;
        gemm_nn<<<dim3(1, 16), blk, 0, stream>>>(Ez, Wq + z * 4096, qb, 1024, 64, 64, 64, 64, 64, nullptr);
        gemm_nn<<<dim3(1, 16), blk, 0, stream>>>(Ez, Wk + z * 4096, kb, 1024, 64, 64, 64, 64, 64, nullptr);
        gemm_nt<<<dim3(16, 16), blk, 0, stream>>>(qb, kb, logits, 1024, 64, 0.125f);
        row_softmax<<<1024, blk, 0, stream>>>(logits, attnf, 1024, McatB[z] + 2048, 3072, 0);
        transpose_f2b<<<dim3(16, 16), blk, 0, stream>>>(attnf, attnT);
        gemm_nt<<<dim3(16, 16), blk, 0, stream>>>(Eg1 + z * 16384, Eg2 + z * 16384, logits, 1024, 16, 1.f);
        row_softmax<<<1024, blk, 0, stream>>>(logits, nullptr, 0, adpb, 1024, 1);
        gemm_mfma<1, 0><<<dim3(8, 8), blk, 0, stream>>>(adjb, attnT, McatB[z],
            1024, 1024, 1024, 1024, 1024, 3072, nullptr, 1024);
        gemm_mfma<1, 0><<<dim3(8, 8), blk, 0, stream>>>(adpb, attnT, McatB[z] + 1024,
            1024, 1024, 1024, 1024, 1024, 3072, nullptr, 1024);
        if (z == 0) {
            for (int kp = 0; kp < 3; ++kp)
                gemm_nn<<<dim3(1, 1), blk, 0, stream>>>(Wv0, Wmix + kp * 4096,
                    Wvc0 + kp * 3 * 64, 3, 64, 64, 64, 64, 64, nullptr);
        } else {
            for (int kp = 0; kp < 3; ++kp)
                gemm_nn<<<dim3(1, 1), blk, 0, stream>>>(Wv1, Wmix + 12288 + kp * 4096,
                    Wvc1 + kp * 4096, 64, 64, 64, 64, 64, 64, nullptr);
            wvc1t_kernel<<<64, blk, 0, stream>>>(Wvc1, Wvc1T);
        }
        wgct_kernel<<<64, blk, 0, stream>>>(Wg + z * 16384, WgcT[z]);
        bias_kernel<<<1, blk, 0, stream>>>(bv + z * 64, Wmix + z * 12288, bmix + z * 64,
            Wg + z * 16384, bg + z * 256, bgc[z]);
    }

    const int nch = L_ / LC;
    dim3 blk512(512);
    for (int c = 0; c < nch; ++c) {
        const int l0 = c * LC;
        // ---- layer 0 ----
        vcat0T_kernel<<<dim3(LC * 16, 4), blk, 0, stream>>>(hist, Wvc0, VcatT, l0, LC);
        gemm_pipe<<<dim3(LC * 4, 4), blk512, 0, stream>>>(Mcatb0, VcatT, HG,
            LC * 1024, 3072);
        fused_gates_scan<<<1024, blk, 0, stream>>>(HG, WgcT0, bgc0, ct0,
            ht0c, hl0, LC, l0, c == 0);
        // ---- layer 1: V build straight into VcatT (REMAP epilogue) ----
        gemm_mfma<1, 1><<<dim3(8, 2, LC * 16), blk, 0, stream>>>(Wvc1T, ht0c, VcatT,
            256, 1024, 64, 64, LC * 1024, 0, nullptr, 192);
        gemm_pipe<<<dim3(LC * 4, 4), blk512, 0, stream>>>(Mcatb1, VcatT, HG,
            LC * 1024, 3072);
        fused_gates_scan<<<1024, blk, 0, stream>>>(HG, WgcT1, bgc1, ct1,
            nullptr, hl1, LC, l0, c == 0);
    }
    decoder_kernel<<<64, blk, 0, stream>>>(hl0, hl1, Wdec, bdec, Wout, bout, outp);
}